// Round 2
// baseline (433.395 us; speedup 1.0000x reference)
//
#include <hip/hip_runtime.h>
#include <stdint.h>

#define V_N 50000
#define E_N 25000
#define NNZ_N 200000
#define CHUNK 2048
// F_IN=128, HID=256, D=4, H1=16, C=40

// ---------------- utility ----------------
__global__ __launch_bounds__(256) void k_zero(int* __restrict__ p, int n) {
  int i = blockIdx.x * 256 + threadIdx.x;
  if (i < n) p[i] = 0;
}

// ---------------- weight fusion ----------------
// Wf0[f, d*16+j] = sum_h Wlin[f, d*256+h] * W0[h, j]
// u1[f, d]       = sum_h Wlin[f, d*256+h] * w1[h, d]   (u2 with w2)
// cb[d*16+j]     = sum_h blin[d*256+h]*W0[h,j]   (goes INSIDE apply_L input)
// bf0[d*16+j]    = b0[j]                          (added after apply_L)
// sbias[d]       = bs[d] + sum_h blin[d*256+h]*(w1[h,d]+w2[h,d])
__global__ __launch_bounds__(64) void k_fuse(
    const float* __restrict__ Wlin, const float* __restrict__ blin,
    const float* __restrict__ w1, const float* __restrict__ w2,
    const float* __restrict__ bs, const float* __restrict__ W0,
    const float* __restrict__ b0,
    float* __restrict__ Wf0, float* __restrict__ u1, float* __restrict__ u2,
    float* __restrict__ cb, float* __restrict__ bf0, float* __restrict__ sbias)
{
  __shared__ float row[1024];
  int f = blockIdx.x;
  for (int t = threadIdx.x; t < 1024; t += 64) row[t] = Wlin[f * 1024 + t];
  __syncthreads();
  int j = threadIdx.x;
  int d = j >> 4, jj = j & 15;
  float acc = 0.f;
  for (int h = 0; h < 256; ++h) acc += row[d * 256 + h] * W0[h * 16 + jj];
  Wf0[f * 64 + j] = acc;
  if (j < 4) {
    float a1 = 0.f, a2 = 0.f;
    for (int h = 0; h < 256; ++h) {
      a1 += row[j * 256 + h] * w1[h * 4 + j];
      a2 += row[j * 256 + h] * w2[h * 4 + j];
    }
    u1[f * 4 + j] = a1;
    u2[f * 4 + j] = a2;
  }
  if (f == 0) {
    float ab = 0.f;
    for (int h = 0; h < 256; ++h) ab += blin[d * 256 + h] * W0[h * 16 + jj];
    cb[j] = ab;
    bf0[j] = b0[jj];
    if (j < 4) {
      float sb = bs[j];
      for (int h = 0; h < 256; ++h) sb += blin[j * 256 + h] * (w1[h * 4 + j] + w2[h * 4 + j]);
      sbias[j] = sb;
    }
  }
}

// ---------------- degrees ----------------
__global__ __launch_bounds__(256) void k_degrees(
    const int* __restrict__ node_idx, const int* __restrict__ edge_idx,
    int* __restrict__ degE, int* __restrict__ degV)
{
  int i = blockIdx.x * 256 + threadIdx.x;
  if (i < NNZ_N) {
    atomicAdd(&degE[edge_idx[i]], 1);
    atomicAdd(&degV[node_idx[i]], 1);
  }
}

// ---------------- scans (exclusive) ----------------
__global__ __launch_bounds__(256) void k_scanA(
    const int* __restrict__ degE, const int* __restrict__ degV,
    int* __restrict__ offE, int* __restrict__ offV,
    int* __restrict__ bsumE, int* __restrict__ bsumV, int nchunkE)
{
  bool isE = (int)blockIdx.x < nchunkE;
  const int* deg = isE ? degE : degV;
  int* off = isE ? offE : offV;
  int* bsum = isE ? bsumE : bsumV;
  int n = isE ? E_N : V_N;
  int chunk = isE ? blockIdx.x : (blockIdx.x - nchunkE);
  int base = chunk * CHUNK;
  int tid = threadIdx.x;
  int vals[8];
  int tsum = 0;
  for (int it = 0; it < 8; ++it) {
    int idx = base + tid * 8 + it;
    int v = (idx < n) ? deg[idx] : 0;
    vals[it] = tsum;
    tsum += v;
  }
  __shared__ int sA[256], sB[256];
  sA[tid] = tsum;
  __syncthreads();
  int* src = sA; int* dst = sB;
  for (int sh = 1; sh < 256; sh <<= 1) {
    dst[tid] = src[tid] + (tid >= sh ? src[tid - sh] : 0);
    __syncthreads();
    int* t = src; src = dst; dst = t;
  }
  int excl = src[tid] - tsum;
  for (int it = 0; it < 8; ++it) {
    int idx = base + tid * 8 + it;
    if (idx < n) off[idx] = excl + vals[it];
  }
  if (tid == 255) bsum[chunk] = src[255];
}

__global__ __launch_bounds__(64) void k_scanB(
    int* __restrict__ bsumE, int* __restrict__ bsumV, int nchunkE, int nchunkV)
{
  if (threadIdx.x == 0) {
    int* b = (blockIdx.x == 0) ? bsumE : bsumV;
    int n = (blockIdx.x == 0) ? nchunkE : nchunkV;
    int run = 0;
    for (int i = 0; i < n; ++i) { int v = b[i]; b[i] = run; run += v; }
  }
}

__global__ __launch_bounds__(256) void k_scanC_inv(
    int* __restrict__ offE, int* __restrict__ offV,
    const int* __restrict__ bsumE, const int* __restrict__ bsumV,
    const int* __restrict__ degE, const int* __restrict__ degV,
    float* __restrict__ invE, float* __restrict__ invV, int nchunkE)
{
  bool isE = (int)blockIdx.x < nchunkE;
  int* off = isE ? offE : offV;
  const int* bsum = isE ? bsumE : bsumV;
  const int* deg = isE ? degE : degV;
  float* inv = isE ? invE : invV;
  int n = isE ? E_N : V_N;
  int chunk = isE ? blockIdx.x : (blockIdx.x - nchunkE);
  int base = chunk * CHUNK;
  int add = bsum[chunk];
  for (int it = 0; it < 8; ++it) {
    int idx = base + threadIdx.x * 8 + it;
    if (idx < n) {
      off[idx] += add;
      int dg = deg[idx];
      inv[idx] = dg > 0 ? 1.0f / (float)dg : 0.0f;
    }
  }
}

// ---------------- front GEMMs ----------------
// node side: G0 = x @ Wf0 + cb  [V,64], svx = x @ u1  [V,4]
// edge side: sex = eattr @ u2 [E,4]
__global__ __launch_bounds__(256) void k_gemm_front(
    const float* __restrict__ x, const float* __restrict__ eattr,
    const float* __restrict__ Wf0, const float* __restrict__ u1, const float* __restrict__ u2,
    const float* __restrict__ cb,
    float* __restrict__ G0, float* __restrict__ svx, float* __restrict__ sex, int nbNode)
{
  __shared__ float Xt[64 * 68];     // 64 rows x 64 k-half, pad 68
  __shared__ float Ws[128 * 64];
  __shared__ float us[512];
  __shared__ float cbs[64];
  int tid = threadIdx.x;
  bool nodeSide = (int)blockIdx.x < nbNode;
  int blk = nodeSide ? blockIdx.x : (blockIdx.x - nbNode);
  const float* src = nodeSide ? x : eattr;
  int nrows = nodeSide ? V_N : E_N;
  int row0 = blk * 64;
  const float* uptr = nodeSide ? u1 : u2;
  for (int k2 = tid; k2 < 512; k2 += 256) us[k2] = uptr[k2];
  if (nodeSide) {
    for (int k2 = tid; k2 < 8192; k2 += 256) Ws[k2] = Wf0[k2];
    if (tid < 64) cbs[tid] = cb[tid];
  }
  int ty = tid >> 4, tx = tid & 15;
  float acc[4][4] = {{0.f}};
  float acc2 = 0.f;
  int rowS = tid >> 2, dS = tid & 3;

  for (int h = 0; h < 2; ++h) {
    __syncthreads();
    for (int c = 0; c < 4; ++c) {
      int fi = c * 1024 + tid * 4;
      int r = fi >> 6, col = fi & 63;
      int gr = row0 + r;
      float4 val = make_float4(0.f, 0.f, 0.f, 0.f);
      if (gr < nrows) val = *(const float4*)(src + (size_t)gr * 128 + h * 64 + col);
      *(float4*)(&Xt[r * 68 + col]) = val;
    }
    __syncthreads();
    if (nodeSide) {
      for (int k0 = 0; k0 < 64; k0 += 4) {
        float A_[4][4], W_[4][4];
        #pragma unroll
        for (int i = 0; i < 4; ++i)
          *(float4*)&A_[i][0] = *(const float4*)&Xt[(ty * 4 + i) * 68 + k0];
        #pragma unroll
        for (int kk = 0; kk < 4; ++kk)
          *(float4*)&W_[kk][0] = *(const float4*)&Ws[(h * 64 + k0 + kk) * 64 + tx * 4];
        #pragma unroll
        for (int i = 0; i < 4; ++i)
          #pragma unroll
          for (int kk = 0; kk < 4; ++kk)
            #pragma unroll
            for (int j = 0; j < 4; ++j)
              acc[i][j] += A_[i][kk] * W_[kk][j];
      }
    }
    {
      float a2 = 0.f;
      for (int k = 0; k < 64; ++k)
        a2 += Xt[rowS * 68 + k] * us[(h * 64 + k) * 4 + dS];
      acc2 += a2;
    }
  }
  if (nodeSide) {
    #pragma unroll
    for (int i = 0; i < 4; ++i) {
      int gr = row0 + ty * 4 + i;
      if (gr < V_N)
        *(float4*)(G0 + (size_t)gr * 64 + tx * 4) =
            make_float4(acc[i][0] + cbs[tx * 4 + 0], acc[i][1] + cbs[tx * 4 + 1],
                        acc[i][2] + cbs[tx * 4 + 2], acc[i][3] + cbs[tx * 4 + 3]);
    }
    int gr = row0 + rowS;
    if (gr < V_N) svx[gr * 4 + dS] = acc2;
  } else {
    int gr = row0 + rowS;
    if (gr < E_N) sex[gr * 4 + dS] = acc2;
  }
}

// ---------------- CSR fill + s ----------------
__global__ __launch_bounds__(256) void k_fill_s(
    const int* __restrict__ node_idx, const int* __restrict__ edge_idx,
    const int* __restrict__ offE, const int* __restrict__ offV,
    int* __restrict__ curE, int* __restrict__ curV,
    int* __restrict__ csrE, int* __restrict__ csrV,
    const float* __restrict__ svx, const float* __restrict__ sex,
    const float* __restrict__ sbias, float* __restrict__ s)
{
  int i = blockIdx.x * 256 + threadIdx.x;
  if (i >= NNZ_N) return;
  int v = node_idx[i], e = edge_idx[i];
  int pe = atomicAdd(&curE[e], 1);
  csrE[offE[e] + pe] = i;
  int pv = atomicAdd(&curV[v], 1);
  csrV[offV[v] + pv] = i;
  float4 a = *(const float4*)(svx + (size_t)v * 4);
  float4 b = *(const float4*)(sex + (size_t)e * 4);
  float4 sb = *(const float4*)(sbias);
  float4 r;
  r.x = tanhf(a.x + b.x + sb.x);
  r.y = tanhf(a.y + b.y + sb.y);
  r.z = tanhf(a.z + b.z + sb.z);
  r.w = tanhf(a.w + b.w + sb.w);
  *(float4*)(s + (size_t)i * 4) = r;
}

// ---------------- sheaf Laplacian stages (c=16 per d, 64 channels flat) ----------------
__global__ __launch_bounds__(256) void k_eagg(
    const float* __restrict__ Hin, const float* __restrict__ s,
    const int* __restrict__ csrE, const int* __restrict__ offE, const int* __restrict__ degE,
    const int* __restrict__ node_idx, const float* __restrict__ invE,
    float* __restrict__ m)
{
  int g = threadIdx.x >> 6, lane = threadIdx.x & 63;
  int e = blockIdx.x * 4 + g;
  if (e >= E_N) return;
  int o0 = offE[e], dg = degE[e];
  int d = lane >> 4;
  float acc = 0.f;
  for (int t = 0; t < dg; ++t) {
    int i = csrE[o0 + t];
    int v = node_idx[i];
    acc += s[(size_t)i * 4 + d] * Hin[(size_t)v * 64 + lane];
  }
  m[(size_t)e * 64 + lane] = acc * invE[e];
}

__global__ __launch_bounds__(256) void k_nagg(
    const float* __restrict__ base, const float* __restrict__ m, const float* __restrict__ s,
    const int* __restrict__ csrV, const int* __restrict__ offV, const int* __restrict__ degV,
    const int* __restrict__ edge_idx, const float* __restrict__ invV,
    const float* __restrict__ bf0, int doRelu, float* __restrict__ outF)
{
  int g = threadIdx.x >> 6, lane = threadIdx.x & 63;
  int v = blockIdx.x * 4 + g;
  if (v >= V_N) return;
  int o0 = offV[v], dg = degV[v];
  int d = lane >> 4;
  float acc = 0.f;
  for (int t = 0; t < dg; ++t) {
    int i = csrV[o0 + t];
    int e = edge_idx[i];
    acc += s[(size_t)i * 4 + d] * m[(size_t)e * 64 + lane];
  }
  float r = base[(size_t)v * 64 + lane] - invV[v] * acc;
  if (doRelu) r = fmaxf(r + bf0[lane], 0.f);
  outF[(size_t)v * 64 + lane] = r;
}

// ---------------- fused tail: H2 = relu(A@W1+b1); out = H2.reshape @ W2 ----------------
__global__ __launch_bounds__(256) void k_final(
    const float* __restrict__ A, const float* __restrict__ W1, const float* __restrict__ b1,
    const float* __restrict__ W2, float* __restrict__ out)
{
  __shared__ float As[16 * 64];
  __shared__ float t[16 * 160];
  __shared__ float W1s[640];
  __shared__ float W2s[6400];
  __shared__ float b1s[40];
  int tid = threadIdx.x;
  int v0 = blockIdx.x * 16;
  for (int k = tid; k < 640; k += 256) W1s[k] = W1[k];
  for (int k = tid; k < 6400; k += 256) W2s[k] = W2[k];
  if (tid < 40) b1s[tid] = b1[tid];
  ((float4*)As)[tid] = ((const float4*)(A + (size_t)v0 * 64))[tid];
  __syncthreads();
  for (int o = tid; o < 16 * 160; o += 256) {
    int n = o / 160, dj = o % 160, d = dj / 40, j = dj % 40;
    float acc = b1s[j];
    const float* a = &As[n * 64 + d * 16];
    #pragma unroll
    for (int c = 0; c < 16; ++c) acc += a[c] * W1s[c * 40 + j];
    t[o] = fmaxf(acc, 0.f);
  }
  __syncthreads();
  for (int o = tid; o < 16 * 40; o += 256) {
    int n = o / 40, k = o % 40;
    float acc = 0.f;
    const float* tn = &t[n * 160];
    for (int mm = 0; mm < 160; ++mm) acc += tn[mm] * W2s[mm * 40 + k];
    out[(size_t)(v0 + n) * 40 + k] = acc;
  }
}

extern "C" void kernel_launch(void* const* d_in, const int* in_sizes, int n_in,
                              void* d_out, int out_size, void* d_ws, size_t ws_size,
                              hipStream_t stream) {
  (void)in_sizes; (void)n_in; (void)out_size; (void)ws_size;
  const float* x = (const float*)d_in[0];
  const float* eattr = (const float*)d_in[1];
  const int* node_idx = (const int*)d_in[2];
  const int* edge_idx = (const int*)d_in[3];
  const float* Wlin = (const float*)d_in[4];
  const float* blin = (const float*)d_in[5];
  const float* w1 = (const float*)d_in[6];
  const float* w2 = (const float*)d_in[7];
  const float* bs = (const float*)d_in[8];
  const float* W0 = (const float*)d_in[9];
  const float* b0 = (const float*)d_in[10];
  const float* W1 = (const float*)d_in[11];
  const float* b1 = (const float*)d_in[12];
  const float* W2 = (const float*)d_in[13];
  float* out = (float*)d_out;

  char* p = (char*)d_ws;
  auto alloc = [&](size_t bytes) { char* q = p; p += (bytes + 255) & ~(size_t)255; return q; };
  float* Wf0   = (float*)alloc(8192 * 4);
  float* u1    = (float*)alloc(512 * 4);
  float* u2    = (float*)alloc(512 * 4);
  float* cbv   = (float*)alloc(64 * 4);
  float* bf0   = (float*)alloc(64 * 4);
  float* sbias = (float*)alloc(4 * 4);
  float* G0    = (float*)alloc((size_t)V_N * 64 * 4);  // reused as A in layer 2
  float* Hb    = (float*)alloc((size_t)V_N * 64 * 4);
  float* mb    = (float*)alloc((size_t)E_N * 64 * 4);  // reused for both eagg passes
  float* svx   = (float*)alloc((size_t)V_N * 4 * 4);
  float* sex   = (float*)alloc((size_t)E_N * 4 * 4);
  float* s     = (float*)alloc((size_t)NNZ_N * 4 * 4);
  float* invE  = (float*)alloc(E_N * 4);
  float* invV  = (float*)alloc(V_N * 4);
  int* zeroRegion = (int*)alloc((size_t)(2 * E_N + 2 * V_N) * 4);
  int* degE = zeroRegion;
  int* degV = degE + E_N;
  int* curE = degV + V_N;
  int* curV = curE + E_N;
  int* offE  = (int*)alloc(E_N * 4);
  int* offV  = (int*)alloc(V_N * 4);
  int* csrE  = (int*)alloc((size_t)NNZ_N * 4);
  int* csrV  = (int*)alloc((size_t)NNZ_N * 4);
  int* bsumE = (int*)alloc(64 * 4);
  int* bsumV = (int*)alloc(64 * 4);

  int nZero = 2 * E_N + 2 * V_N;
  int nchunkE = (E_N + CHUNK - 1) / CHUNK;   // 13
  int nchunkV = (V_N + CHUNK - 1) / CHUNK;   // 25
  int nbNode = (V_N + 63) / 64;              // 782
  int nbEdge = (E_N + 63) / 64;              // 391

  hipLaunchKernelGGL(k_zero, dim3((nZero + 255) / 256), dim3(256), 0, stream, zeroRegion, nZero);
  hipLaunchKernelGGL(k_fuse, dim3(128), dim3(64), 0, stream,
                     Wlin, blin, w1, w2, bs, W0, b0, Wf0, u1, u2, cbv, bf0, sbias);
  hipLaunchKernelGGL(k_degrees, dim3((NNZ_N + 255) / 256), dim3(256), 0, stream,
                     node_idx, edge_idx, degE, degV);
  hipLaunchKernelGGL(k_scanA, dim3(nchunkE + nchunkV), dim3(256), 0, stream,
                     degE, degV, offE, offV, bsumE, bsumV, nchunkE);
  hipLaunchKernelGGL(k_scanB, dim3(2), dim3(64), 0, stream, bsumE, bsumV, nchunkE, nchunkV);
  hipLaunchKernelGGL(k_scanC_inv, dim3(nchunkE + nchunkV), dim3(256), 0, stream,
                     offE, offV, bsumE, bsumV, degE, degV, invE, invV, nchunkE);
  hipLaunchKernelGGL(k_gemm_front, dim3(nbNode + nbEdge), dim3(256), 0, stream,
                     x, eattr, Wf0, u1, u2, cbv, G0, svx, sex, nbNode);
  hipLaunchKernelGGL(k_fill_s, dim3((NNZ_N + 255) / 256), dim3(256), 0, stream,
                     node_idx, edge_idx, offE, offV, curE, curV, csrE, csrV, svx, sex, sbias, s);
  hipLaunchKernelGGL(k_eagg, dim3((E_N + 3) / 4), dim3(256), 0, stream,
                     G0, s, csrE, offE, degE, node_idx, invE, mb);
  hipLaunchKernelGGL(k_nagg, dim3((V_N + 3) / 4), dim3(256), 0, stream,
                     G0, mb, s, csrV, offV, degV, edge_idx, invV, bf0, 1, Hb);
  hipLaunchKernelGGL(k_eagg, dim3((E_N + 3) / 4), dim3(256), 0, stream,
                     Hb, s, csrE, offE, degE, node_idx, invE, mb);
  hipLaunchKernelGGL(k_nagg, dim3((V_N + 3) / 4), dim3(256), 0, stream,
                     Hb, mb, s, csrV, offV, degV, edge_idx, invV, bf0, 0, G0);
  hipLaunchKernelGGL(k_final, dim3(V_N / 16), dim3(256), 0, stream, G0, W1, b1, W2, out);
}

// Round 4
// 336.188 us; speedup vs baseline: 1.2891x; 1.2891x over previous
//
#include <hip/hip_runtime.h>
#include <stdint.h>

#define V_N 50000
#define E_N 25000
#define NNZ_N 200000
#define CHUNK 2048
// F_IN=128, HID=256, D=4, H1=16, C=40

// ---------------- utility ----------------
__global__ __launch_bounds__(256) void k_zero(int* __restrict__ p, int n) {
  int i = blockIdx.x * 256 + threadIdx.x;
  if (i < n) p[i] = 0;
}

// ---------------- weight fusion ----------------
__global__ __launch_bounds__(64) void k_fuse(
    const float* __restrict__ Wlin, const float* __restrict__ blin,
    const float* __restrict__ w1, const float* __restrict__ w2,
    const float* __restrict__ bs, const float* __restrict__ W0,
    const float* __restrict__ b0,
    float* __restrict__ Wf0, float* __restrict__ u1, float* __restrict__ u2,
    float* __restrict__ cb, float* __restrict__ bf0, float* __restrict__ sbias)
{
  __shared__ float row[1024];
  int f = blockIdx.x;
  for (int t = threadIdx.x; t < 1024; t += 64) row[t] = Wlin[f * 1024 + t];
  __syncthreads();
  int j = threadIdx.x;
  int d = j >> 4, jj = j & 15;
  float acc = 0.f;
  for (int h = 0; h < 256; ++h) acc += row[d * 256 + h] * W0[h * 16 + jj];
  Wf0[f * 64 + j] = acc;
  if (j < 4) {
    float a1 = 0.f, a2 = 0.f;
    for (int h = 0; h < 256; ++h) {
      a1 += row[j * 256 + h] * w1[h * 4 + j];
      a2 += row[j * 256 + h] * w2[h * 4 + j];
    }
    u1[f * 4 + j] = a1;
    u2[f * 4 + j] = a2;
  }
  if (f == 0) {
    float ab = 0.f;
    for (int h = 0; h < 256; ++h) ab += blin[d * 256 + h] * W0[h * 16 + jj];
    cb[j] = ab;
    bf0[j] = b0[jj];
    if (j < 4) {
      float sb = bs[j];
      for (int h = 0; h < 256; ++h) sb += blin[j * 256 + h] * (w1[h * 4 + j] + w2[h * 4 + j]);
      sbias[j] = sb;
    }
  }
}

// ---------------- degrees ----------------
__global__ __launch_bounds__(256) void k_degrees(
    const int* __restrict__ node_idx, const int* __restrict__ edge_idx,
    int* __restrict__ degE, int* __restrict__ degV)
{
  int i = blockIdx.x * 256 + threadIdx.x;
  if (i < NNZ_N) {
    atomicAdd(&degE[edge_idx[i]], 1);
    atomicAdd(&degV[node_idx[i]], 1);
  }
}

// ---------------- scans (exclusive) ----------------
__global__ __launch_bounds__(256) void k_scanA(
    const int* __restrict__ degE, const int* __restrict__ degV,
    int* __restrict__ offE, int* __restrict__ offV,
    int* __restrict__ bsumE, int* __restrict__ bsumV, int nchunkE)
{
  bool isE = (int)blockIdx.x < nchunkE;
  const int* deg = isE ? degE : degV;
  int* off = isE ? offE : offV;
  int* bsum = isE ? bsumE : bsumV;
  int n = isE ? E_N : V_N;
  int chunk = isE ? blockIdx.x : (blockIdx.x - nchunkE);
  int base = chunk * CHUNK;
  int tid = threadIdx.x;
  int vals[8];
  int tsum = 0;
  for (int it = 0; it < 8; ++it) {
    int idx = base + tid * 8 + it;
    int v = (idx < n) ? deg[idx] : 0;
    vals[it] = tsum;
    tsum += v;
  }
  __shared__ int sA[256], sB[256];
  sA[tid] = tsum;
  __syncthreads();
  int* src = sA; int* dst = sB;
  for (int sh = 1; sh < 256; sh <<= 1) {
    dst[tid] = src[tid] + (tid >= sh ? src[tid - sh] : 0);
    __syncthreads();
    int* t = src; src = dst; dst = t;
  }
  int excl = src[tid] - tsum;
  for (int it = 0; it < 8; ++it) {
    int idx = base + tid * 8 + it;
    if (idx < n) off[idx] = excl + vals[it];
  }
  if (tid == 255) bsum[chunk] = src[255];
}

__global__ __launch_bounds__(64) void k_scanB(
    int* __restrict__ bsumE, int* __restrict__ bsumV, int nchunkE, int nchunkV)
{
  if (threadIdx.x == 0) {
    int* b = (blockIdx.x == 0) ? bsumE : bsumV;
    int n = (blockIdx.x == 0) ? nchunkE : nchunkV;
    int run = 0;
    for (int i = 0; i < n; ++i) { int v = b[i]; b[i] = run; run += v; }
  }
}

__global__ __launch_bounds__(256) void k_scanC_inv(
    int* __restrict__ offE, int* __restrict__ offV,
    const int* __restrict__ bsumE, const int* __restrict__ bsumV,
    const int* __restrict__ degE, const int* __restrict__ degV,
    float* __restrict__ invE, float* __restrict__ invV, int nchunkE)
{
  bool isE = (int)blockIdx.x < nchunkE;
  int* off = isE ? offE : offV;
  const int* bsum = isE ? bsumE : bsumV;
  const int* deg = isE ? degE : degV;
  float* inv = isE ? invE : invV;
  int n = isE ? E_N : V_N;
  int chunk = isE ? blockIdx.x : (blockIdx.x - nchunkE);
  int base = chunk * CHUNK;
  int add = bsum[chunk];
  for (int it = 0; it < 8; ++it) {
    int idx = base + threadIdx.x * 8 + it;
    if (idx < n) {
      off[idx] += add;
      int dg = deg[idx];
      inv[idx] = dg > 0 ? 1.0f / (float)dg : 0.0f;
    }
  }
}

// ---------------- front GEMMs ----------------
__global__ __launch_bounds__(256) void k_gemm_front(
    const float* __restrict__ x, const float* __restrict__ eattr,
    const float* __restrict__ Wf0, const float* __restrict__ u1, const float* __restrict__ u2,
    const float* __restrict__ cb,
    float* __restrict__ G0, float* __restrict__ svx, float* __restrict__ sex, int nbNode)
{
  __shared__ float Xt[64 * 68];
  __shared__ float Ws[128 * 64];
  __shared__ float us[512];
  __shared__ float cbs[64];
  int tid = threadIdx.x;
  bool nodeSide = (int)blockIdx.x < nbNode;
  int blk = nodeSide ? blockIdx.x : (blockIdx.x - nbNode);
  const float* src = nodeSide ? x : eattr;
  int nrows = nodeSide ? V_N : E_N;
  int row0 = blk * 64;
  const float* uptr = nodeSide ? u1 : u2;
  for (int k2 = tid; k2 < 512; k2 += 256) us[k2] = uptr[k2];
  if (nodeSide) {
    for (int k2 = tid; k2 < 8192; k2 += 256) Ws[k2] = Wf0[k2];
    if (tid < 64) cbs[tid] = cb[tid];
  }
  int ty = tid >> 4, tx = tid & 15;
  float acc[4][4] = {{0.f}};
  float acc2 = 0.f;
  int rowS = tid >> 2, dS = tid & 3;

  for (int h = 0; h < 2; ++h) {
    __syncthreads();
    for (int c = 0; c < 4; ++c) {
      int fi = c * 1024 + tid * 4;
      int r = fi >> 6, col = fi & 63;
      int gr = row0 + r;
      float4 val = make_float4(0.f, 0.f, 0.f, 0.f);
      if (gr < nrows) val = *(const float4*)(src + (size_t)gr * 128 + h * 64 + col);
      *(float4*)(&Xt[r * 68 + col]) = val;
    }
    __syncthreads();
    if (nodeSide) {
      for (int k0 = 0; k0 < 64; k0 += 4) {
        float A_[4][4], W_[4][4];
        #pragma unroll
        for (int i = 0; i < 4; ++i)
          *(float4*)&A_[i][0] = *(const float4*)&Xt[(ty * 4 + i) * 68 + k0];
        #pragma unroll
        for (int kk = 0; kk < 4; ++kk)
          *(float4*)&W_[kk][0] = *(const float4*)&Ws[(h * 64 + k0 + kk) * 64 + tx * 4];
        #pragma unroll
        for (int i = 0; i < 4; ++i)
          #pragma unroll
          for (int kk = 0; kk < 4; ++kk)
            #pragma unroll
            for (int j = 0; j < 4; ++j)
              acc[i][j] += A_[i][kk] * W_[kk][j];
      }
    }
    {
      float a2 = 0.f;
      for (int k = 0; k < 64; ++k)
        a2 += Xt[rowS * 68 + k] * us[(h * 64 + k) * 4 + dS];
      acc2 += a2;
    }
  }
  if (nodeSide) {
    #pragma unroll
    for (int i = 0; i < 4; ++i) {
      int gr = row0 + ty * 4 + i;
      if (gr < V_N)
        *(float4*)(G0 + (size_t)gr * 64 + tx * 4) =
            make_float4(acc[i][0] + cbs[tx * 4 + 0], acc[i][1] + cbs[tx * 4 + 1],
                        acc[i][2] + cbs[tx * 4 + 2], acc[i][3] + cbs[tx * 4 + 3]);
    }
    int gr = row0 + rowS;
    if (gr < V_N) svx[gr * 4 + dS] = acc2;
  } else {
    int gr = row0 + rowS;
    if (gr < E_N) sex[gr * 4 + dS] = acc2;
  }
}

// ---------------- CSR fill + permuted s payloads (inv pre-folded) ----------------
__global__ __launch_bounds__(256) void k_fill_s(
    const int* __restrict__ node_idx, const int* __restrict__ edge_idx,
    const int* __restrict__ offE, const int* __restrict__ offV,
    int* __restrict__ curE, int* __restrict__ curV,
    int* __restrict__ csrEv, int* __restrict__ csrVe,
    float* __restrict__ sE4, float* __restrict__ sV4,
    const float* __restrict__ svx, const float* __restrict__ sex,
    const float* __restrict__ sbias,
    const float* __restrict__ invE, const float* __restrict__ invV)
{
  int i = blockIdx.x * 256 + threadIdx.x;
  if (i >= NNZ_N) return;
  int v = node_idx[i], e = edge_idx[i];
  float4 a = *(const float4*)(svx + (size_t)v * 4);
  float4 b = *(const float4*)(sex + (size_t)e * 4);
  float4 sb = *(const float4*)(sbias);
  float4 r;
  r.x = tanhf(a.x + b.x + sb.x);
  r.y = tanhf(a.y + b.y + sb.y);
  r.z = tanhf(a.z + b.z + sb.z);
  r.w = tanhf(a.w + b.w + sb.w);
  float ie = invE[e], iv = invV[v];
  int pe = atomicAdd(&curE[e], 1);
  int slotE = offE[e] + pe;
  csrEv[slotE] = v;
  float4 re = make_float4(r.x * ie, r.y * ie, r.z * ie, r.w * ie);
  *(float4*)(sE4 + (size_t)slotE * 4) = re;
  int pv = atomicAdd(&curV[v], 1);
  int slotV = offV[v] + pv;
  csrVe[slotV] = e;
  float4 rv = make_float4(r.x * iv, r.y * iv, r.z * iv, r.w * iv);
  *(float4*)(sV4 + (size_t)slotV * 4) = rv;
}

// ---------------- sheaf Laplacian stages (shfl-broadcast gathers) ----------------
__global__ __launch_bounds__(256) void k_eagg(
    const float* __restrict__ Hin, const int* __restrict__ csrEv,
    const float* __restrict__ sE4,
    const int* __restrict__ offE, const int* __restrict__ degE,
    float* __restrict__ m)
{
  int g = threadIdx.x >> 6, lane = threadIdx.x & 63;
  int e = blockIdx.x * 4 + g;
  if (e >= E_N) return;
  int o0 = offE[e], dg = degE[e];
  int dsh = (lane >> 4) & 3;
  float acc = 0.f;
  for (int base = 0; base < dg; base += 16) {
    int idx = base + (lane & 15);
    int vv = (idx < dg) ? csrEv[o0 + idx] : 0;
    int sidx = base * 4 + lane;
    float ss = (sidx < dg * 4) ? sE4[(size_t)o0 * 4 + sidx] : 0.f;
    int lim = min(16, dg - base);
    #pragma unroll 4
    for (int t = 0; t < lim; ++t) {
      int v = __shfl(vv, t);
      float sv = __shfl(ss, t * 4 + dsh);
      acc += sv * Hin[(size_t)v * 64 + lane];
    }
  }
  m[(size_t)e * 64 + lane] = acc;   // invE folded into sE4
}

__global__ __launch_bounds__(256) void k_nagg(
    const float* __restrict__ base_, const float* __restrict__ m,
    const int* __restrict__ csrVe, const float* __restrict__ sV4,
    const int* __restrict__ offV, const int* __restrict__ degV,
    const float* __restrict__ bf0, int doRelu, float* __restrict__ outF)
{
  int g = threadIdx.x >> 6, lane = threadIdx.x & 63;
  int v = blockIdx.x * 4 + g;
  if (v >= V_N) return;
  int o0 = offV[v], dg = degV[v];
  int dsh = (lane >> 4) & 3;
  float acc = 0.f;
  for (int base = 0; base < dg; base += 16) {
    int idx = base + (lane & 15);
    int ee = (idx < dg) ? csrVe[o0 + idx] : 0;
    int sidx = base * 4 + lane;
    float ss = (sidx < dg * 4) ? sV4[(size_t)o0 * 4 + sidx] : 0.f;
    int lim = min(16, dg - base);
    #pragma unroll 4
    for (int t = 0; t < lim; ++t) {
      int e = __shfl(ee, t);
      float sv = __shfl(ss, t * 4 + dsh);
      acc += sv * m[(size_t)e * 64 + lane];
    }
  }
  float r = base_[(size_t)v * 64 + lane] - acc;   // invV folded into sV4
  if (doRelu) r = fmaxf(r + bf0[lane], 0.f);
  outF[(size_t)v * 64 + lane] = r;
}

// ---------------- fused tail v2: register-tiled, 32 rows/block ----------------
// phase 1: t[32][160] = relu(A-block-diag @ W1 + b1); A in registers from global
// phase 2: out[32][40] = t @ W2, 2x4 register tile
__global__ __launch_bounds__(256) void k_final(
    const float* __restrict__ A, const float* __restrict__ W1, const float* __restrict__ b1,
    const float* __restrict__ W2, float* __restrict__ out)
{
  __shared__ float W2s[160 * 40];   // 25600 B
  __shared__ float t[32 * 164];     // 20992 B (pad 164 breaks stride-160 banks)
  __shared__ float W1s[640];
  __shared__ float b1s[40];
  int tid = threadIdx.x;
  int v0 = blockIdx.x * 32;

  for (int k = tid; k < 1600; k += 256) ((float4*)W2s)[k] = ((const float4*)W2)[k];
  for (int k = tid; k < 640; k += 256) W1s[k] = W1[k];
  if (tid < 40) b1s[tid] = b1[tid];
  __syncthreads();

  if (tid < 160) {
    // phase 1: rg = row group (4 rows), cg = col group (8 of 160 t-cols)
    int rg = tid / 20, cg = tid % 20;
    int r0 = rg * 4;
    int j0 = cg * 8;
    int d = cg / 5;              // = (cg*8)/40
    int jloc = j0 - d * 40;      // W1 col base
    float a[4][16];
    #pragma unroll
    for (int i = 0; i < 4; ++i) {
      int gr = v0 + r0 + i;
      #pragma unroll
      for (int c4 = 0; c4 < 4; ++c4) {
        float4 val = make_float4(0.f, 0.f, 0.f, 0.f);
        if (gr < V_N) val = *(const float4*)(A + (size_t)gr * 64 + d * 16 + c4 * 4);
        *(float4*)&a[i][c4 * 4] = val;
      }
    }
    float acc1[4][8];
    #pragma unroll
    for (int i = 0; i < 4; ++i)
      #pragma unroll
      for (int jj = 0; jj < 8; ++jj) acc1[i][jj] = b1s[jloc + jj];
    #pragma unroll
    for (int c = 0; c < 16; ++c) {
      float w[8];
      *(float4*)&w[0] = *(const float4*)&W1s[c * 40 + jloc];
      *(float4*)&w[4] = *(const float4*)&W1s[c * 40 + jloc + 4];
      #pragma unroll
      for (int i = 0; i < 4; ++i)
        #pragma unroll
        for (int jj = 0; jj < 8; ++jj)
          acc1[i][jj] += a[i][c] * w[jj];
    }
    #pragma unroll
    for (int i = 0; i < 4; ++i) {
      float4 lo = make_float4(fmaxf(acc1[i][0], 0.f), fmaxf(acc1[i][1], 0.f),
                              fmaxf(acc1[i][2], 0.f), fmaxf(acc1[i][3], 0.f));
      float4 hi = make_float4(fmaxf(acc1[i][4], 0.f), fmaxf(acc1[i][5], 0.f),
                              fmaxf(acc1[i][6], 0.f), fmaxf(acc1[i][7], 0.f));
      *(float4*)&t[(r0 + i) * 164 + j0] = lo;
      *(float4*)&t[(r0 + i) * 164 + j0 + 4] = hi;
    }
  }
  __syncthreads();

  if (tid < 160) {
    // phase 2: rg2 = row pair (2 rows), cg2 = 4 cols
    int rg2 = tid / 10, cg2 = tid % 10;
    float acc2[2][4] = {{0.f, 0.f, 0.f, 0.f}, {0.f, 0.f, 0.f, 0.f}};
    for (int k0 = 0; k0 < 160; k0 += 4) {
      float a0[4], a1[4], w[4][4];
      *(float4*)a0 = *(const float4*)&t[(rg2 * 2 + 0) * 164 + k0];
      *(float4*)a1 = *(const float4*)&t[(rg2 * 2 + 1) * 164 + k0];
      #pragma unroll
      for (int kk = 0; kk < 4; ++kk)
        *(float4*)&w[kk][0] = *(const float4*)&W2s[(k0 + kk) * 40 + cg2 * 4];
      #pragma unroll
      for (int kk = 0; kk < 4; ++kk)
        #pragma unroll
        for (int j = 0; j < 4; ++j) {
          acc2[0][j] += a0[kk] * w[kk][j];
          acc2[1][j] += a1[kk] * w[kk][j];
        }
    }
    #pragma unroll
    for (int i = 0; i < 2; ++i) {
      int gr = v0 + rg2 * 2 + i;
      if (gr < V_N)
        *(float4*)(out + (size_t)gr * 40 + cg2 * 4) =
            make_float4(acc2[i][0], acc2[i][1], acc2[i][2], acc2[i][3]);
    }
  }
}

extern "C" void kernel_launch(void* const* d_in, const int* in_sizes, int n_in,
                              void* d_out, int out_size, void* d_ws, size_t ws_size,
                              hipStream_t stream) {
  (void)in_sizes; (void)n_in; (void)out_size; (void)ws_size;
  const float* x = (const float*)d_in[0];
  const float* eattr = (const float*)d_in[1];
  const int* node_idx = (const int*)d_in[2];
  const int* edge_idx = (const int*)d_in[3];
  const float* Wlin = (const float*)d_in[4];
  const float* blin = (const float*)d_in[5];
  const float* w1 = (const float*)d_in[6];
  const float* w2 = (const float*)d_in[7];
  const float* bs = (const float*)d_in[8];
  const float* W0 = (const float*)d_in[9];
  const float* b0 = (const float*)d_in[10];
  const float* W1 = (const float*)d_in[11];
  const float* b1 = (const float*)d_in[12];
  const float* W2 = (const float*)d_in[13];
  float* out = (float*)d_out;

  char* p = (char*)d_ws;
  auto alloc = [&](size_t bytes) { char* q = p; p += (bytes + 255) & ~(size_t)255; return q; };
  float* Wf0   = (float*)alloc(8192 * 4);
  float* u1    = (float*)alloc(512 * 4);
  float* u2    = (float*)alloc(512 * 4);
  float* cbv   = (float*)alloc(64 * 4);
  float* bf0   = (float*)alloc(64 * 4);
  float* sbias = (float*)alloc(4 * 4);
  float* G0    = (float*)alloc((size_t)V_N * 64 * 4);  // reused as A in layer 2
  float* Hb    = (float*)alloc((size_t)V_N * 64 * 4);
  float* mb    = (float*)alloc((size_t)E_N * 64 * 4);  // reused for both eagg passes
  float* svx   = (float*)alloc((size_t)V_N * 4 * 4);
  float* sex   = (float*)alloc((size_t)E_N * 4 * 4);
  float* sE4   = (float*)alloc((size_t)NNZ_N * 4 * 4);
  float* sV4   = (float*)alloc((size_t)NNZ_N * 4 * 4);
  float* invE  = (float*)alloc(E_N * 4);
  float* invV  = (float*)alloc(V_N * 4);
  int* zeroRegion = (int*)alloc((size_t)(2 * E_N + 2 * V_N) * 4);
  int* degE = zeroRegion;
  int* degV = degE + E_N;
  int* curE = degV + V_N;
  int* curV = curE + E_N;
  int* offE  = (int*)alloc(E_N * 4);
  int* offV  = (int*)alloc(V_N * 4);
  int* csrEv = (int*)alloc((size_t)NNZ_N * 4);
  int* csrVe = (int*)alloc((size_t)NNZ_N * 4);
  int* bsumE = (int*)alloc(64 * 4);
  int* bsumV = (int*)alloc(64 * 4);

  int nZero = 2 * E_N + 2 * V_N;
  int nchunkE = (E_N + CHUNK - 1) / CHUNK;   // 13
  int nchunkV = (V_N + CHUNK - 1) / CHUNK;   // 25
  int nbNode = (V_N + 63) / 64;              // 782
  int nbEdge = (E_N + 63) / 64;              // 391

  hipLaunchKernelGGL(k_zero, dim3((nZero + 255) / 256), dim3(256), 0, stream, zeroRegion, nZero);
  hipLaunchKernelGGL(k_fuse, dim3(128), dim3(64), 0, stream,
                     Wlin, blin, w1, w2, bs, W0, b0, Wf0, u1, u2, cbv, bf0, sbias);
  hipLaunchKernelGGL(k_degrees, dim3((NNZ_N + 255) / 256), dim3(256), 0, stream,
                     node_idx, edge_idx, degE, degV);
  hipLaunchKernelGGL(k_scanA, dim3(nchunkE + nchunkV), dim3(256), 0, stream,
                     degE, degV, offE, offV, bsumE, bsumV, nchunkE);
  hipLaunchKernelGGL(k_scanB, dim3(2), dim3(64), 0, stream, bsumE, bsumV, nchunkE, nchunkV);
  hipLaunchKernelGGL(k_scanC_inv, dim3(nchunkE + nchunkV), dim3(256), 0, stream,
                     offE, offV, bsumE, bsumV, degE, degV, invE, invV, nchunkE);
  hipLaunchKernelGGL(k_gemm_front, dim3(nbNode + nbEdge), dim3(256), 0, stream,
                     x, eattr, Wf0, u1, u2, cbv, G0, svx, sex, nbNode);
  hipLaunchKernelGGL(k_fill_s, dim3((NNZ_N + 255) / 256), dim3(256), 0, stream,
                     node_idx, edge_idx, offE, offV, curE, curV, csrEv, csrVe,
                     sE4, sV4, svx, sex, sbias, invE, invV);
  hipLaunchKernelGGL(k_eagg, dim3((E_N + 3) / 4), dim3(256), 0, stream,
                     G0, csrEv, sE4, offE, degE, mb);
  hipLaunchKernelGGL(k_nagg, dim3((V_N + 3) / 4), dim3(256), 0, stream,
                     G0, mb, csrVe, sV4, offV, degV, bf0, 1, Hb);
  hipLaunchKernelGGL(k_eagg, dim3((E_N + 3) / 4), dim3(256), 0, stream,
                     Hb, csrEv, sE4, offE, degE, mb);
  hipLaunchKernelGGL(k_nagg, dim3((V_N + 3) / 4), dim3(256), 0, stream,
                     Hb, mb, csrVe, sV4, offV, degV, bf0, 0, G0);
  hipLaunchKernelGGL(k_final, dim3((V_N + 31) / 32), dim3(256), 0, stream, G0, W1, b1, W2, out);
}

// Round 7
// 329.135 us; speedup vs baseline: 1.3168x; 1.0214x over previous
//
#include <hip/hip_runtime.h>
#include <stdint.h>

#define V_N 50000
#define E_N 25000
#define NNZ_N 200000
#define CHUNK 2048
// F_IN=128, HID=256, D=4, H1=16, C=40

// ---------------- utility ----------------
__global__ __launch_bounds__(256) void k_zero(int* __restrict__ p, int n) {
  int i = blockIdx.x * 256 + threadIdx.x;
  if (i < n) p[i] = 0;
}

// ---------------- weight fusion ----------------
__global__ __launch_bounds__(64) void k_fuse(
    const float* __restrict__ Wlin, const float* __restrict__ blin,
    const float* __restrict__ w1, const float* __restrict__ w2,
    const float* __restrict__ bs, const float* __restrict__ W0,
    const float* __restrict__ b0,
    float* __restrict__ Wf0, float* __restrict__ u1, float* __restrict__ u2,
    float* __restrict__ cb, float* __restrict__ bf0, float* __restrict__ sbias)
{
  __shared__ float row[1024];
  int f = blockIdx.x;
  for (int t = threadIdx.x; t < 1024; t += 64) row[t] = Wlin[f * 1024 + t];
  __syncthreads();
  int j = threadIdx.x;
  int d = j >> 4, jj = j & 15;
  float acc = 0.f;
  for (int h = 0; h < 256; ++h) acc += row[d * 256 + h] * W0[h * 16 + jj];
  Wf0[f * 64 + j] = acc;
  if (j < 4) {
    float a1 = 0.f, a2 = 0.f;
    for (int h = 0; h < 256; ++h) {
      a1 += row[j * 256 + h] * w1[h * 4 + j];
      a2 += row[j * 256 + h] * w2[h * 4 + j];
    }
    u1[f * 4 + j] = a1;
    u2[f * 4 + j] = a2;
  }
  if (f == 0) {
    float ab = 0.f;
    for (int h = 0; h < 256; ++h) ab += blin[d * 256 + h] * W0[h * 16 + jj];
    cb[j] = ab;
    bf0[j] = b0[jj];
    if (j < 4) {
      float sb = bs[j];
      for (int h = 0; h < 256; ++h) sb += blin[j * 256 + h] * (w1[h * 4 + j] + w2[h * 4 + j]);
      sbias[j] = sb;
    }
  }
}

// ---------------- degrees ----------------
__global__ __launch_bounds__(256) void k_degrees(
    const int* __restrict__ node_idx, const int* __restrict__ edge_idx,
    int* __restrict__ degE, int* __restrict__ degV)
{
  int i = blockIdx.x * 256 + threadIdx.x;
  if (i < NNZ_N) {
    atomicAdd(&degE[edge_idx[i]], 1);
    atomicAdd(&degV[node_idx[i]], 1);
  }
}

// ---------------- scans (exclusive) ----------------
__global__ __launch_bounds__(256) void k_scanA(
    const int* __restrict__ degE, const int* __restrict__ degV,
    int* __restrict__ offE, int* __restrict__ offV,
    int* __restrict__ bsumE, int* __restrict__ bsumV, int nchunkE)
{
  bool isE = (int)blockIdx.x < nchunkE;
  const int* deg = isE ? degE : degV;
  int* off = isE ? offE : offV;
  int* bsum = isE ? bsumE : bsumV;
  int n = isE ? E_N : V_N;
  int chunk = isE ? blockIdx.x : (blockIdx.x - nchunkE);
  int base = chunk * CHUNK;
  int tid = threadIdx.x;
  int vals[8];
  int tsum = 0;
  for (int it = 0; it < 8; ++it) {
    int idx = base + tid * 8 + it;
    int v = (idx < n) ? deg[idx] : 0;
    vals[it] = tsum;
    tsum += v;
  }
  __shared__ int sA[256], sB[256];
  sA[tid] = tsum;
  __syncthreads();
  int* src = sA; int* dst = sB;
  for (int sh = 1; sh < 256; sh <<= 1) {
    dst[tid] = src[tid] + (tid >= sh ? src[tid - sh] : 0);
    __syncthreads();
    int* t = src; src = dst; dst = t;
  }
  int excl = src[tid] - tsum;
  for (int it = 0; it < 8; ++it) {
    int idx = base + tid * 8 + it;
    if (idx < n) off[idx] = excl + vals[it];
  }
  if (tid == 255) bsum[chunk] = src[255];
}

__global__ __launch_bounds__(64) void k_scanB(
    int* __restrict__ bsumE, int* __restrict__ bsumV, int nchunkE, int nchunkV)
{
  if (threadIdx.x == 0) {
    int* b = (blockIdx.x == 0) ? bsumE : bsumV;
    int n = (blockIdx.x == 0) ? nchunkE : nchunkV;
    int run = 0;
    for (int i = 0; i < n; ++i) { int v = b[i]; b[i] = run; run += v; }
  }
}

__global__ __launch_bounds__(256) void k_scanC_inv(
    int* __restrict__ offE, int* __restrict__ offV,
    const int* __restrict__ bsumE, const int* __restrict__ bsumV,
    const int* __restrict__ degE, const int* __restrict__ degV,
    float* __restrict__ invE, float* __restrict__ invV, int nchunkE)
{
  bool isE = (int)blockIdx.x < nchunkE;
  int* off = isE ? offE : offV;
  const int* bsum = isE ? bsumE : bsumV;
  const int* deg = isE ? degE : degV;
  float* inv = isE ? invE : invV;
  int n = isE ? E_N : V_N;
  int chunk = isE ? blockIdx.x : (blockIdx.x - nchunkE);
  int base = chunk * CHUNK;
  int add = bsum[chunk];
  for (int it = 0; it < 8; ++it) {
    int idx = base + threadIdx.x * 8 + it;
    if (idx < n) {
      off[idx] += add;
      int dg = deg[idx];
      inv[idx] = dg > 0 ? 1.0f / (float)dg : 0.0f;
    }
  }
}

// ---------------- node GEMM: G0 = x @ Wf0 + cb [V,64], svx = x @ u1 [V,4] ----------------
// X-tile staged once (pad 132); W streamed from global into registers (L1/L2-resident).
__global__ __launch_bounds__(256) void k_gemm_node(
    const float* __restrict__ x, const float* __restrict__ Wf0,
    const float* __restrict__ u1, const float* __restrict__ cb,
    float* __restrict__ G0, float* __restrict__ svx)
{
  __shared__ float Xt[64 * 132];   // 33792 B
  __shared__ float us[512];        // u1 [128][4]
  int tid = threadIdx.x;
  int row0 = blockIdx.x * 64;
  #pragma unroll
  for (int it = 0; it < 8; ++it) {
    int fi = it * 1024 + tid * 4;
    int r = fi >> 7, c = fi & 127;
    float4 val = make_float4(0.f, 0.f, 0.f, 0.f);
    int gr = row0 + r;
    if (gr < V_N) val = *(const float4*)(x + (size_t)gr * 128 + c);
    *(float4*)&Xt[r * 132 + c] = val;
  }
  for (int k2 = tid; k2 < 512; k2 += 256) us[k2] = u1[k2];
  int ty = tid >> 4, tx = tid & 15;
  float4 cbr = *(const float4*)(cb + tx * 4);
  __syncthreads();

  float acc[4][4];
  #pragma unroll
  for (int i = 0; i < 4; ++i) {
    acc[i][0] = cbr.x; acc[i][1] = cbr.y; acc[i][2] = cbr.z; acc[i][3] = cbr.w;
  }
  #pragma unroll 2
  for (int k0 = 0; k0 < 128; k0 += 4) {
    float A_[4][4], W_[4][4];
    #pragma unroll
    for (int kk = 0; kk < 4; ++kk)
      *(float4*)&W_[kk][0] = *(const float4*)(Wf0 + (size_t)(k0 + kk) * 64 + tx * 4);
    #pragma unroll
    for (int i = 0; i < 4; ++i)
      *(float4*)&A_[i][0] = *(const float4*)&Xt[(ty * 4 + i) * 132 + k0];
    #pragma unroll
    for (int i = 0; i < 4; ++i)
      #pragma unroll
      for (int kk = 0; kk < 4; ++kk)
        #pragma unroll
        for (int j = 0; j < 4; ++j)
          acc[i][j] += A_[i][kk] * W_[kk][j];
  }
  #pragma unroll
  for (int i = 0; i < 4; ++i) {
    int gr = row0 + ty * 4 + i;
    if (gr < V_N)
      *(float4*)(G0 + (size_t)gr * 64 + tx * 4) =
          make_float4(acc[i][0], acc[i][1], acc[i][2], acc[i][3]);
  }
  // svx: 256 threads = 64 rows x 4 d; Xt reads are near-conflict-free via pad 132
  int rs = tid >> 2, dS = tid & 3;
  float a2 = 0.f;
  for (int k = 0; k < 128; ++k)
    a2 += Xt[rs * 132 + k] * us[k * 4 + dS];
  int gr = row0 + rs;
  if (gr < V_N) svx[gr * 4 + dS] = a2;
}

// ---------------- edge GEMM: sex = eattr @ u2 [E,4] (slim) ----------------
__global__ __launch_bounds__(256) void k_gemm_edge(
    const float* __restrict__ eattr, const float* __restrict__ u2,
    float* __restrict__ sex)
{
  __shared__ float Xt[64 * 132];
  __shared__ float us[512];
  int tid = threadIdx.x;
  int row0 = blockIdx.x * 64;
  #pragma unroll
  for (int it = 0; it < 8; ++it) {
    int fi = it * 1024 + tid * 4;
    int r = fi >> 7, c = fi & 127;
    float4 val = make_float4(0.f, 0.f, 0.f, 0.f);
    int gr = row0 + r;
    if (gr < E_N) val = *(const float4*)(eattr + (size_t)gr * 128 + c);
    *(float4*)&Xt[r * 132 + c] = val;
  }
  for (int k2 = tid; k2 < 512; k2 += 256) us[k2] = u2[k2];
  __syncthreads();
  int rs = tid >> 2, dS = tid & 3;
  float a2 = 0.f;
  for (int k = 0; k < 128; ++k)
    a2 += Xt[rs * 132 + k] * us[k * 4 + dS];
  int gr = row0 + rs;
  if (gr < E_N) sex[gr * 4 + dS] = a2;
}

// ---------------- CSR fill + permuted s payloads (inv pre-folded) ----------------
__global__ __launch_bounds__(256) void k_fill_s(
    const int* __restrict__ node_idx, const int* __restrict__ edge_idx,
    const int* __restrict__ offE, const int* __restrict__ offV,
    int* __restrict__ curE, int* __restrict__ curV,
    int* __restrict__ csrEv, int* __restrict__ csrVe,
    float* __restrict__ sE4, float* __restrict__ sV4,
    const float* __restrict__ svx, const float* __restrict__ sex,
    const float* __restrict__ sbias,
    const float* __restrict__ invE, const float* __restrict__ invV)
{
  int i = blockIdx.x * 256 + threadIdx.x;
  if (i >= NNZ_N) return;
  int v = node_idx[i], e = edge_idx[i];
  float4 a = *(const float4*)(svx + (size_t)v * 4);
  float4 b = *(const float4*)(sex + (size_t)e * 4);
  float4 sb = *(const float4*)(sbias);
  float4 r;
  r.x = tanhf(a.x + b.x + sb.x);
  r.y = tanhf(a.y + b.y + sb.y);
  r.z = tanhf(a.z + b.z + sb.z);
  r.w = tanhf(a.w + b.w + sb.w);
  float ie = invE[e], iv = invV[v];
  int pe = atomicAdd(&curE[e], 1);
  int slotE = offE[e] + pe;
  csrEv[slotE] = v;
  float4 re = make_float4(r.x * ie, r.y * ie, r.z * ie, r.w * ie);
  *(float4*)(sE4 + (size_t)slotE * 4) = re;
  int pv = atomicAdd(&curV[v], 1);
  int slotV = offV[v] + pv;
  csrVe[slotV] = e;
  float4 rv = make_float4(r.x * iv, r.y * iv, r.z * iv, r.w * iv);
  *(float4*)(sV4 + (size_t)slotV * 4) = rv;
}

// ---------------- sheaf Laplacian stages (shfl-broadcast gathers) ----------------
__global__ __launch_bounds__(256) void k_eagg(
    const float* __restrict__ Hin, const int* __restrict__ csrEv,
    const float* __restrict__ sE4,
    const int* __restrict__ offE, const int* __restrict__ degE,
    float* __restrict__ m)
{
  int g = threadIdx.x >> 6, lane = threadIdx.x & 63;
  int e = blockIdx.x * 4 + g;
  if (e >= E_N) return;
  int o0 = offE[e], dg = degE[e];
  int dsh = (lane >> 4) & 3;
  float acc = 0.f;
  for (int base = 0; base < dg; base += 16) {
    int idx = base + (lane & 15);
    int vv = (idx < dg) ? csrEv[o0 + idx] : 0;
    int sidx = base * 4 + lane;
    float ss = (sidx < dg * 4) ? sE4[(size_t)o0 * 4 + sidx] : 0.f;
    int lim = min(16, dg - base);
    #pragma unroll 4
    for (int t = 0; t < lim; ++t) {
      int v = __shfl(vv, t);
      float sv = __shfl(ss, t * 4 + dsh);
      acc += sv * Hin[(size_t)v * 64 + lane];
    }
  }
  m[(size_t)e * 64 + lane] = acc;   // invE folded into sE4
}

__global__ __launch_bounds__(256) void k_nagg(
    const float* __restrict__ base_, const float* __restrict__ m,
    const int* __restrict__ csrVe, const float* __restrict__ sV4,
    const int* __restrict__ offV, const int* __restrict__ degV,
    const float* __restrict__ bf0, int doRelu, float* __restrict__ outF)
{
  int g = threadIdx.x >> 6, lane = threadIdx.x & 63;
  int v = blockIdx.x * 4 + g;
  if (v >= V_N) return;
  int o0 = offV[v], dg = degV[v];
  int dsh = (lane >> 4) & 3;
  float acc = 0.f;
  for (int base = 0; base < dg; base += 16) {
    int idx = base + (lane & 15);
    int ee = (idx < dg) ? csrVe[o0 + idx] : 0;
    int sidx = base * 4 + lane;
    float ss = (sidx < dg * 4) ? sV4[(size_t)o0 * 4 + sidx] : 0.f;
    int lim = min(16, dg - base);
    #pragma unroll 4
    for (int t = 0; t < lim; ++t) {
      int e = __shfl(ee, t);
      float sv = __shfl(ss, t * 4 + dsh);
      acc += sv * m[(size_t)e * 64 + lane];
    }
  }
  float r = base_[(size_t)v * 64 + lane] - acc;   // invV folded into sV4
  if (doRelu) r = fmaxf(r + bf0[lane], 0.f);
  outF[(size_t)v * 64 + lane] = r;
}

// ---------------- fused tail: register-tiled, 32 rows/block ----------------
__global__ __launch_bounds__(256) void k_final(
    const float* __restrict__ A, const float* __restrict__ W1, const float* __restrict__ b1,
    const float* __restrict__ W2, float* __restrict__ out)
{
  __shared__ float W2s[160 * 40];
  __shared__ float t[32 * 164];
  __shared__ float W1s[640];
  __shared__ float b1s[40];
  int tid = threadIdx.x;
  int v0 = blockIdx.x * 32;

  for (int k = tid; k < 1600; k += 256) ((float4*)W2s)[k] = ((const float4*)W2)[k];
  for (int k = tid; k < 640; k += 256) W1s[k] = W1[k];
  if (tid < 40) b1s[tid] = b1[tid];
  __syncthreads();

  if (tid < 160) {
    int rg = tid / 20, cg = tid % 20;
    int r0 = rg * 4;
    int j0 = cg * 8;
    int d = cg / 5;
    int jloc = j0 - d * 40;
    float a[4][16];
    #pragma unroll
    for (int i = 0; i < 4; ++i) {
      int gr = v0 + r0 + i;
      #pragma unroll
      for (int c4 = 0; c4 < 4; ++c4) {
        float4 val = make_float4(0.f, 0.f, 0.f, 0.f);
        if (gr < V_N) val = *(const float4*)(A + (size_t)gr * 64 + d * 16 + c4 * 4);
        *(float4*)&a[i][c4 * 4] = val;
      }
    }
    float acc1[4][8];
    #pragma unroll
    for (int i = 0; i < 4; ++i)
      #pragma unroll
      for (int jj = 0; jj < 8; ++jj) acc1[i][jj] = b1s[jloc + jj];
    #pragma unroll
    for (int c = 0; c < 16; ++c) {
      float w[8];
      *(float4*)&w[0] = *(const float4*)&W1s[c * 40 + jloc];
      *(float4*)&w[4] = *(const float4*)&W1s[c * 40 + jloc + 4];
      #pragma unroll
      for (int i = 0; i < 4; ++i)
        #pragma unroll
        for (int jj = 0; jj < 8; ++jj)
          acc1[i][jj] += a[i][c] * w[jj];
    }
    #pragma unroll
    for (int i = 0; i < 4; ++i) {
      float4 lo = make_float4(fmaxf(acc1[i][0], 0.f), fmaxf(acc1[i][1], 0.f),
                              fmaxf(acc1[i][2], 0.f), fmaxf(acc1[i][3], 0.f));
      float4 hi = make_float4(fmaxf(acc1[i][4], 0.f), fmaxf(acc1[i][5], 0.f),
                              fmaxf(acc1[i][6], 0.f), fmaxf(acc1[i][7], 0.f));
      *(float4*)&t[(r0 + i) * 164 + j0] = lo;
      *(float4*)&t[(r0 + i) * 164 + j0 + 4] = hi;
    }
  }
  __syncthreads();

  if (tid < 160) {
    int rg2 = tid / 10, cg2 = tid % 10;
    float acc2[2][4] = {{0.f, 0.f, 0.f, 0.f}, {0.f, 0.f, 0.f, 0.f}};
    for (int k0 = 0; k0 < 160; k0 += 4) {
      float a0[4], a1[4], w[4][4];
      *(float4*)a0 = *(const float4*)&t[(rg2 * 2 + 0) * 164 + k0];
      *(float4*)a1 = *(const float4*)&t[(rg2 * 2 + 1) * 164 + k0];
      #pragma unroll
      for (int kk = 0; kk < 4; ++kk)
        *(float4*)&w[kk][0] = *(const float4*)&W2s[(k0 + kk) * 40 + cg2 * 4];
      #pragma unroll
      for (int kk = 0; kk < 4; ++kk)
        #pragma unroll
        for (int j = 0; j < 4; ++j) {
          acc2[0][j] += a0[kk] * w[kk][j];
          acc2[1][j] += a1[kk] * w[kk][j];
        }
    }
    #pragma unroll
    for (int i = 0; i < 2; ++i) {
      int gr = v0 + rg2 * 2 + i;
      if (gr < V_N)
        *(float4*)(out + (size_t)gr * 40 + cg2 * 4) =
            make_float4(acc2[i][0], acc2[i][1], acc2[i][2], acc2[i][3]);
    }
  }
}

extern "C" void kernel_launch(void* const* d_in, const int* in_sizes, int n_in,
                              void* d_out, int out_size, void* d_ws, size_t ws_size,
                              hipStream_t stream) {
  (void)in_sizes; (void)n_in; (void)out_size; (void)ws_size;
  const float* x = (const float*)d_in[0];
  const float* eattr = (const float*)d_in[1];
  const int* node_idx = (const int*)d_in[2];
  const int* edge_idx = (const int*)d_in[3];
  const float* Wlin = (const float*)d_in[4];
  const float* blin = (const float*)d_in[5];
  const float* w1 = (const float*)d_in[6];
  const float* w2 = (const float*)d_in[7];
  const float* bs = (const float*)d_in[8];
  const float* W0 = (const float*)d_in[9];
  const float* b0 = (const float*)d_in[10];
  const float* W1 = (const float*)d_in[11];
  const float* b1 = (const float*)d_in[12];
  const float* W2 = (const float*)d_in[13];
  float* out = (float*)d_out;

  char* p = (char*)d_ws;
  auto alloc = [&](size_t bytes) { char* q = p; p += (bytes + 255) & ~(size_t)255; return q; };
  float* Wf0   = (float*)alloc(8192 * 4);
  float* u1    = (float*)alloc(512 * 4);
  float* u2    = (float*)alloc(512 * 4);
  float* cbv   = (float*)alloc(64 * 4);
  float* bf0   = (float*)alloc(64 * 4);
  float* sbias = (float*)alloc(4 * 4);
  float* G0    = (float*)alloc((size_t)V_N * 64 * 4);  // reused as A in layer 2
  float* Hb    = (float*)alloc((size_t)V_N * 64 * 4);
  float* mb    = (float*)alloc((size_t)E_N * 64 * 4);  // reused for both eagg passes
  float* svx   = (float*)alloc((size_t)V_N * 4 * 4);
  float* sex   = (float*)alloc((size_t)E_N * 4 * 4);
  float* sE4   = (float*)alloc((size_t)NNZ_N * 4 * 4);
  float* sV4   = (float*)alloc((size_t)NNZ_N * 4 * 4);
  float* invE  = (float*)alloc(E_N * 4);
  float* invV  = (float*)alloc(V_N * 4);
  int* zeroRegion = (int*)alloc((size_t)(2 * E_N + 2 * V_N) * 4);
  int* degE = zeroRegion;
  int* degV = degE + E_N;
  int* curE = degV + V_N;
  int* curV = curE + E_N;
  int* offE  = (int*)alloc(E_N * 4);
  int* offV  = (int*)alloc(V_N * 4);
  int* csrEv = (int*)alloc((size_t)NNZ_N * 4);
  int* csrVe = (int*)alloc((size_t)NNZ_N * 4);
  int* bsumE = (int*)alloc(64 * 4);
  int* bsumV = (int*)alloc(64 * 4);

  int nZero = 2 * E_N + 2 * V_N;
  int nchunkE = (E_N + CHUNK - 1) / CHUNK;   // 13
  int nchunkV = (V_N + CHUNK - 1) / CHUNK;   // 25
  int nbNode = (V_N + 63) / 64;              // 782
  int nbEdge = (E_N + 63) / 64;              // 391

  hipLaunchKernelGGL(k_zero, dim3((nZero + 255) / 256), dim3(256), 0, stream, zeroRegion, nZero);
  hipLaunchKernelGGL(k_fuse, dim3(128), dim3(64), 0, stream,
                     Wlin, blin, w1, w2, bs, W0, b0, Wf0, u1, u2, cbv, bf0, sbias);
  hipLaunchKernelGGL(k_degrees, dim3((NNZ_N + 255) / 256), dim3(256), 0, stream,
                     node_idx, edge_idx, degE, degV);
  hipLaunchKernelGGL(k_scanA, dim3(nchunkE + nchunkV), dim3(256), 0, stream,
                     degE, degV, offE, offV, bsumE, bsumV, nchunkE);
  hipLaunchKernelGGL(k_scanB, dim3(2), dim3(64), 0, stream, bsumE, bsumV, nchunkE, nchunkV);
  hipLaunchKernelGGL(k_scanC_inv, dim3(nchunkE + nchunkV), dim3(256), 0, stream,
                     offE, offV, bsumE, bsumV, degE, degV, invE, invV, nchunkE);
  hipLaunchKernelGGL(k_gemm_node, dim3(nbNode), dim3(256), 0, stream,
                     x, Wf0, u1, cbv, G0, svx);
  hipLaunchKernelGGL(k_gemm_edge, dim3(nbEdge), dim3(256), 0, stream,
                     eattr, u2, sex);
  hipLaunchKernelGGL(k_fill_s, dim3((NNZ_N + 255) / 256), dim3(256), 0, stream,
                     node_idx, edge_idx, offE, offV, curE, curV, csrEv, csrVe,
                     sE4, sV4, svx, sex, sbias, invE, invV);
  hipLaunchKernelGGL(k_eagg, dim3((E_N + 3) / 4), dim3(256), 0, stream,
                     G0, csrEv, sE4, offE, degE, mb);
  hipLaunchKernelGGL(k_nagg, dim3((V_N + 3) / 4), dim3(256), 0, stream,
                     G0, mb, csrVe, sV4, offV, degV, bf0, 1, Hb);
  hipLaunchKernelGGL(k_eagg, dim3((E_N + 3) / 4), dim3(256), 0, stream,
                     Hb, csrEv, sE4, offE, degE, mb);
  hipLaunchKernelGGL(k_nagg, dim3((V_N + 3) / 4), dim3(256), 0, stream,
                     Hb, mb, csrVe, sV4, offV, degV, bf0, 0, G0);
  hipLaunchKernelGGL(k_final, dim3((V_N + 31) / 32), dim3(256), 0, stream, G0, W1, b1, W2, out);
}

// Round 8
// 325.028 us; speedup vs baseline: 1.3334x; 1.0126x over previous
//
#include <hip/hip_runtime.h>
#include <hip/hip_fp16.h>
#include <stdint.h>

#define V_N 50000
#define E_N 25000
#define NNZ_N 200000
#define CHUNK 2048
// F_IN=128, HID=256, D=4, H1=16, C=40

// ---------------- utility ----------------
__global__ __launch_bounds__(256) void k_zero(int* __restrict__ p, int n) {
  int i = blockIdx.x * 256 + threadIdx.x;
  if (i < n) p[i] = 0;
}

// ---------------- weight fusion ----------------
__global__ __launch_bounds__(64) void k_fuse(
    const float* __restrict__ Wlin, const float* __restrict__ blin,
    const float* __restrict__ w1, const float* __restrict__ w2,
    const float* __restrict__ bs, const float* __restrict__ W0,
    const float* __restrict__ b0,
    float* __restrict__ Wf0, float* __restrict__ u1, float* __restrict__ u2,
    float* __restrict__ cb, float* __restrict__ bf0, float* __restrict__ sbias)
{
  __shared__ float row[1024];
  int f = blockIdx.x;
  for (int t = threadIdx.x; t < 1024; t += 64) row[t] = Wlin[f * 1024 + t];
  __syncthreads();
  int j = threadIdx.x;
  int d = j >> 4, jj = j & 15;
  float acc = 0.f;
  for (int h = 0; h < 256; ++h) acc += row[d * 256 + h] * W0[h * 16 + jj];
  Wf0[f * 64 + j] = acc;
  if (j < 4) {
    float a1 = 0.f, a2 = 0.f;
    for (int h = 0; h < 256; ++h) {
      a1 += row[j * 256 + h] * w1[h * 4 + j];
      a2 += row[j * 256 + h] * w2[h * 4 + j];
    }
    u1[f * 4 + j] = a1;
    u2[f * 4 + j] = a2;
  }
  if (f == 0) {
    float ab = 0.f;
    for (int h = 0; h < 256; ++h) ab += blin[d * 256 + h] * W0[h * 16 + jj];
    cb[j] = ab;
    bf0[j] = b0[jj];
    if (j < 4) {
      float sb = bs[j];
      for (int h = 0; h < 256; ++h) sb += blin[j * 256 + h] * (w1[h * 4 + j] + w2[h * 4 + j]);
      sbias[j] = sb;
    }
  }
}

// ---------------- degrees ----------------
__global__ __launch_bounds__(256) void k_degrees(
    const int* __restrict__ node_idx, const int* __restrict__ edge_idx,
    int* __restrict__ degE, int* __restrict__ degV)
{
  int i = blockIdx.x * 256 + threadIdx.x;
  if (i < NNZ_N) {
    atomicAdd(&degE[edge_idx[i]], 1);
    atomicAdd(&degV[node_idx[i]], 1);
  }
}

// ---------------- scans (exclusive) ----------------
__global__ __launch_bounds__(256) void k_scanA(
    const int* __restrict__ degE, const int* __restrict__ degV,
    int* __restrict__ offE, int* __restrict__ offV,
    int* __restrict__ bsumE, int* __restrict__ bsumV, int nchunkE)
{
  bool isE = (int)blockIdx.x < nchunkE;
  const int* deg = isE ? degE : degV;
  int* off = isE ? offE : offV;
  int* bsum = isE ? bsumE : bsumV;
  int n = isE ? E_N : V_N;
  int chunk = isE ? blockIdx.x : (blockIdx.x - nchunkE);
  int base = chunk * CHUNK;
  int tid = threadIdx.x;
  int vals[8];
  int tsum = 0;
  for (int it = 0; it < 8; ++it) {
    int idx = base + tid * 8 + it;
    int v = (idx < n) ? deg[idx] : 0;
    vals[it] = tsum;
    tsum += v;
  }
  __shared__ int sA[256], sB[256];
  sA[tid] = tsum;
  __syncthreads();
  int* src = sA; int* dst = sB;
  for (int sh = 1; sh < 256; sh <<= 1) {
    dst[tid] = src[tid] + (tid >= sh ? src[tid - sh] : 0);
    __syncthreads();
    int* t = src; src = dst; dst = t;
  }
  int excl = src[tid] - tsum;
  for (int it = 0; it < 8; ++it) {
    int idx = base + tid * 8 + it;
    if (idx < n) off[idx] = excl + vals[it];
  }
  if (tid == 255) bsum[chunk] = src[255];
}

__global__ __launch_bounds__(64) void k_scanB(
    int* __restrict__ bsumE, int* __restrict__ bsumV, int nchunkE, int nchunkV)
{
  if (threadIdx.x == 0) {
    int* b = (blockIdx.x == 0) ? bsumE : bsumV;
    int n = (blockIdx.x == 0) ? nchunkE : nchunkV;
    int run = 0;
    for (int i = 0; i < n; ++i) { int v = b[i]; b[i] = run; run += v; }
  }
}

__global__ __launch_bounds__(256) void k_scanC_inv(
    int* __restrict__ offE, int* __restrict__ offV,
    const int* __restrict__ bsumE, const int* __restrict__ bsumV,
    const int* __restrict__ degE, const int* __restrict__ degV,
    float* __restrict__ invE, float* __restrict__ invV, int nchunkE)
{
  bool isE = (int)blockIdx.x < nchunkE;
  int* off = isE ? offE : offV;
  const int* bsum = isE ? bsumE : bsumV;
  const int* deg = isE ? degE : degV;
  float* inv = isE ? invE : invV;
  int n = isE ? E_N : V_N;
  int chunk = isE ? blockIdx.x : (blockIdx.x - nchunkE);
  int base = chunk * CHUNK;
  int add = bsum[chunk];
  for (int it = 0; it < 8; ++it) {
    int idx = base + threadIdx.x * 8 + it;
    if (idx < n) {
      off[idx] += add;
      int dg = deg[idx];
      inv[idx] = dg > 0 ? 1.0f / (float)dg : 0.0f;
    }
  }
}

// ---------------- node GEMM: G0h = fp16(x @ Wf0 + cb) [V,64], svx = x @ u1 [V,4] ----------------
__global__ __launch_bounds__(256) void k_gemm_node(
    const float* __restrict__ x, const float* __restrict__ Wf0,
    const float* __restrict__ u1, const float* __restrict__ cb,
    __half* __restrict__ G0h, float* __restrict__ svx)
{
  __shared__ float Xt[64 * 132];   // 33792 B
  __shared__ float us[512];        // u1 [128][4]
  int tid = threadIdx.x;
  int row0 = blockIdx.x * 64;
  #pragma unroll
  for (int it = 0; it < 8; ++it) {
    int fi = it * 1024 + tid * 4;
    int r = fi >> 7, c = fi & 127;
    float4 val = make_float4(0.f, 0.f, 0.f, 0.f);
    int gr = row0 + r;
    if (gr < V_N) val = *(const float4*)(x + (size_t)gr * 128 + c);
    *(float4*)&Xt[r * 132 + c] = val;
  }
  for (int k2 = tid; k2 < 512; k2 += 256) us[k2] = u1[k2];
  int ty = tid >> 4, tx = tid & 15;
  float4 cbr = *(const float4*)(cb + tx * 4);
  __syncthreads();

  float acc[4][4];
  #pragma unroll
  for (int i = 0; i < 4; ++i) {
    acc[i][0] = cbr.x; acc[i][1] = cbr.y; acc[i][2] = cbr.z; acc[i][3] = cbr.w;
  }
  #pragma unroll 2
  for (int k0 = 0; k0 < 128; k0 += 4) {
    float A_[4][4], W_[4][4];
    #pragma unroll
    for (int kk = 0; kk < 4; ++kk)
      *(float4*)&W_[kk][0] = *(const float4*)(Wf0 + (size_t)(k0 + kk) * 64 + tx * 4);
    #pragma unroll
    for (int i = 0; i < 4; ++i)
      *(float4*)&A_[i][0] = *(const float4*)&Xt[(ty * 4 + i) * 132 + k0];
    #pragma unroll
    for (int i = 0; i < 4; ++i)
      #pragma unroll
      for (int kk = 0; kk < 4; ++kk)
        #pragma unroll
        for (int j = 0; j < 4; ++j)
          acc[i][j] += A_[i][kk] * W_[kk][j];
  }
  #pragma unroll
  for (int i = 0; i < 4; ++i) {
    int gr = row0 + ty * 4 + i;
    if (gr < V_N) {
      __half2* dst = (__half2*)(G0h + (size_t)gr * 64 + tx * 4);
      dst[0] = __floats2half2_rn(acc[i][0], acc[i][1]);
      dst[1] = __floats2half2_rn(acc[i][2], acc[i][3]);
    }
  }
  // svx: 256 threads = 64 rows x 4 d
  int rs = tid >> 2, dS = tid & 3;
  float a2 = 0.f;
  for (int k = 0; k < 128; ++k)
    a2 += Xt[rs * 132 + k] * us[k * 4 + dS];
  int gr = row0 + rs;
  if (gr < V_N) svx[gr * 4 + dS] = a2;
}

// ---------------- edge GEMM: sex = eattr @ u2 [E,4] (slim) ----------------
__global__ __launch_bounds__(256) void k_gemm_edge(
    const float* __restrict__ eattr, const float* __restrict__ u2,
    float* __restrict__ sex)
{
  __shared__ float Xt[64 * 132];
  __shared__ float us[512];
  int tid = threadIdx.x;
  int row0 = blockIdx.x * 64;
  #pragma unroll
  for (int it = 0; it < 8; ++it) {
    int fi = it * 1024 + tid * 4;
    int r = fi >> 7, c = fi & 127;
    float4 val = make_float4(0.f, 0.f, 0.f, 0.f);
    int gr = row0 + r;
    if (gr < E_N) val = *(const float4*)(eattr + (size_t)gr * 128 + c);
    *(float4*)&Xt[r * 132 + c] = val;
  }
  for (int k2 = tid; k2 < 512; k2 += 256) us[k2] = u2[k2];
  __syncthreads();
  int rs = tid >> 2, dS = tid & 3;
  float a2 = 0.f;
  for (int k = 0; k < 128; ++k)
    a2 += Xt[rs * 132 + k] * us[k * 4 + dS];
  int gr = row0 + rs;
  if (gr < E_N) sex[gr * 4 + dS] = a2;
}

// ---------------- CSR fill + permuted s payloads (inv pre-folded) ----------------
__global__ __launch_bounds__(256) void k_fill_s(
    const int* __restrict__ node_idx, const int* __restrict__ edge_idx,
    const int* __restrict__ offE, const int* __restrict__ offV,
    int* __restrict__ curE, int* __restrict__ curV,
    int* __restrict__ csrEv, int* __restrict__ csrVe,
    float* __restrict__ sE4, float* __restrict__ sV4,
    const float* __restrict__ svx, const float* __restrict__ sex,
    const float* __restrict__ sbias,
    const float* __restrict__ invE, const float* __restrict__ invV)
{
  int i = blockIdx.x * 256 + threadIdx.x;
  if (i >= NNZ_N) return;
  int v = node_idx[i], e = edge_idx[i];
  float4 a = *(const float4*)(svx + (size_t)v * 4);
  float4 b = *(const float4*)(sex + (size_t)e * 4);
  float4 sb = *(const float4*)(sbias);
  float4 r;
  r.x = tanhf(a.x + b.x + sb.x);
  r.y = tanhf(a.y + b.y + sb.y);
  r.z = tanhf(a.z + b.z + sb.z);
  r.w = tanhf(a.w + b.w + sb.w);
  float ie = invE[e], iv = invV[v];
  int pe = atomicAdd(&curE[e], 1);
  int slotE = offE[e] + pe;
  csrEv[slotE] = v;
  float4 re = make_float4(r.x * ie, r.y * ie, r.z * ie, r.w * ie);
  *(float4*)(sE4 + (size_t)slotE * 4) = re;
  int pv = atomicAdd(&curV[v], 1);
  int slotV = offV[v] + pv;
  csrVe[slotV] = e;
  float4 rv = make_float4(r.x * iv, r.y * iv, r.z * iv, r.w * iv);
  *(float4*)(sV4 + (size_t)slotV * 4) = rv;
}

// ---------------- sheaf Laplacian stages (fp16 feature tables, fp32 accum) ----------------
__global__ __launch_bounds__(256) void k_eagg(
    const __half* __restrict__ Hin, const int* __restrict__ csrEv,
    const float* __restrict__ sE4,
    const int* __restrict__ offE, const int* __restrict__ degE,
    __half* __restrict__ m)
{
  int g = threadIdx.x >> 6, lane = threadIdx.x & 63;
  int e = blockIdx.x * 4 + g;
  if (e >= E_N) return;
  int o0 = offE[e], dg = degE[e];
  int dsh = (lane >> 4) & 3;
  float acc = 0.f;
  for (int base = 0; base < dg; base += 16) {
    int idx = base + (lane & 15);
    int vv = (idx < dg) ? csrEv[o0 + idx] : 0;
    int sidx = base * 4 + lane;
    float ss = (sidx < dg * 4) ? sE4[(size_t)o0 * 4 + sidx] : 0.f;
    int lim = min(16, dg - base);
    #pragma unroll 4
    for (int t = 0; t < lim; ++t) {
      int v = __shfl(vv, t);
      float sv = __shfl(ss, t * 4 + dsh);
      acc += sv * __half2float(Hin[(size_t)v * 64 + lane]);
    }
  }
  m[(size_t)e * 64 + lane] = __float2half(acc);   // invE folded into sE4
}

__global__ __launch_bounds__(256) void k_nagg(
    const __half* __restrict__ base_, const __half* __restrict__ m,
    const int* __restrict__ csrVe, const float* __restrict__ sV4,
    const int* __restrict__ offV, const int* __restrict__ degV,
    const float* __restrict__ bf0, int doRelu,
    __half* __restrict__ outH, float* __restrict__ outF)
{
  int g = threadIdx.x >> 6, lane = threadIdx.x & 63;
  int v = blockIdx.x * 4 + g;
  if (v >= V_N) return;
  int o0 = offV[v], dg = degV[v];
  int dsh = (lane >> 4) & 3;
  float acc = 0.f;
  for (int base = 0; base < dg; base += 16) {
    int idx = base + (lane & 15);
    int ee = (idx < dg) ? csrVe[o0 + idx] : 0;
    int sidx = base * 4 + lane;
    float ss = (sidx < dg * 4) ? sV4[(size_t)o0 * 4 + sidx] : 0.f;
    int lim = min(16, dg - base);
    #pragma unroll 4
    for (int t = 0; t < lim; ++t) {
      int e = __shfl(ee, t);
      float sv = __shfl(ss, t * 4 + dsh);
      acc += sv * __half2float(m[(size_t)e * 64 + lane]);
    }
  }
  float r = __half2float(base_[(size_t)v * 64 + lane]) - acc;  // invV folded into sV4
  if (doRelu) {
    r = fmaxf(r + bf0[lane], 0.f);
    outH[(size_t)v * 64 + lane] = __float2half(r);
  } else {
    outF[(size_t)v * 64 + lane] = r;
  }
}

// ---------------- fused tail: register-tiled, 32 rows/block ----------------
__global__ __launch_bounds__(256) void k_final(
    const float* __restrict__ A, const float* __restrict__ W1, const float* __restrict__ b1,
    const float* __restrict__ W2, float* __restrict__ out)
{
  __shared__ float W2s[160 * 40];
  __shared__ float t[32 * 164];
  __shared__ float W1s[640];
  __shared__ float b1s[40];
  int tid = threadIdx.x;
  int v0 = blockIdx.x * 32;

  for (int k = tid; k < 1600; k += 256) ((float4*)W2s)[k] = ((const float4*)W2)[k];
  for (int k = tid; k < 640; k += 256) W1s[k] = W1[k];
  if (tid < 40) b1s[tid] = b1[tid];
  __syncthreads();

  if (tid < 160) {
    int rg = tid / 20, cg = tid % 20;
    int r0 = rg * 4;
    int j0 = cg * 8;
    int d = cg / 5;
    int jloc = j0 - d * 40;
    float a[4][16];
    #pragma unroll
    for (int i = 0; i < 4; ++i) {
      int gr = v0 + r0 + i;
      #pragma unroll
      for (int c4 = 0; c4 < 4; ++c4) {
        float4 val = make_float4(0.f, 0.f, 0.f, 0.f);
        if (gr < V_N) val = *(const float4*)(A + (size_t)gr * 64 + d * 16 + c4 * 4);
        *(float4*)&a[i][c4 * 4] = val;
      }
    }
    float acc1[4][8];
    #pragma unroll
    for (int i = 0; i < 4; ++i)
      #pragma unroll
      for (int jj = 0; jj < 8; ++jj) acc1[i][jj] = b1s[jloc + jj];
    #pragma unroll
    for (int c = 0; c < 16; ++c) {
      float w[8];
      *(float4*)&w[0] = *(const float4*)&W1s[c * 40 + jloc];
      *(float4*)&w[4] = *(const float4*)&W1s[c * 40 + jloc + 4];
      #pragma unroll
      for (int i = 0; i < 4; ++i)
        #pragma unroll
        for (int jj = 0; jj < 8; ++jj)
          acc1[i][jj] += a[i][c] * w[jj];
    }
    #pragma unroll
    for (int i = 0; i < 4; ++i) {
      float4 lo = make_float4(fmaxf(acc1[i][0], 0.f), fmaxf(acc1[i][1], 0.f),
                              fmaxf(acc1[i][2], 0.f), fmaxf(acc1[i][3], 0.f));
      float4 hi = make_float4(fmaxf(acc1[i][4], 0.f), fmaxf(acc1[i][5], 0.f),
                              fmaxf(acc1[i][6], 0.f), fmaxf(acc1[i][7], 0.f));
      *(float4*)&t[(r0 + i) * 164 + j0] = lo;
      *(float4*)&t[(r0 + i) * 164 + j0 + 4] = hi;
    }
  }
  __syncthreads();

  if (tid < 160) {
    int rg2 = tid / 10, cg2 = tid % 10;
    float acc2[2][4] = {{0.f, 0.f, 0.f, 0.f}, {0.f, 0.f, 0.f, 0.f}};
    for (int k0 = 0; k0 < 160; k0 += 4) {
      float a0[4], a1[4], w[4][4];
      *(float4*)a0 = *(const float4*)&t[(rg2 * 2 + 0) * 164 + k0];
      *(float4*)a1 = *(const float4*)&t[(rg2 * 2 + 1) * 164 + k0];
      #pragma unroll
      for (int kk = 0; kk < 4; ++kk)
        *(float4*)&w[kk][0] = *(const float4*)&W2s[(k0 + kk) * 40 + cg2 * 4];
      #pragma unroll
      for (int kk = 0; kk < 4; ++kk)
        #pragma unroll
        for (int j = 0; j < 4; ++j) {
          acc2[0][j] += a0[kk] * w[kk][j];
          acc2[1][j] += a1[kk] * w[kk][j];
        }
    }
    #pragma unroll
    for (int i = 0; i < 2; ++i) {
      int gr = v0 + rg2 * 2 + i;
      if (gr < V_N)
        *(float4*)(out + (size_t)gr * 40 + cg2 * 4) =
            make_float4(acc2[i][0], acc2[i][1], acc2[i][2], acc2[i][3]);
    }
  }
}

extern "C" void kernel_launch(void* const* d_in, const int* in_sizes, int n_in,
                              void* d_out, int out_size, void* d_ws, size_t ws_size,
                              hipStream_t stream) {
  (void)in_sizes; (void)n_in; (void)out_size; (void)ws_size;
  const float* x = (const float*)d_in[0];
  const float* eattr = (const float*)d_in[1];
  const int* node_idx = (const int*)d_in[2];
  const int* edge_idx = (const int*)d_in[3];
  const float* Wlin = (const float*)d_in[4];
  const float* blin = (const float*)d_in[5];
  const float* w1 = (const float*)d_in[6];
  const float* w2 = (const float*)d_in[7];
  const float* bs = (const float*)d_in[8];
  const float* W0 = (const float*)d_in[9];
  const float* b0 = (const float*)d_in[10];
  const float* W1 = (const float*)d_in[11];
  const float* b1 = (const float*)d_in[12];
  const float* W2 = (const float*)d_in[13];
  float* out = (float*)d_out;

  char* p = (char*)d_ws;
  auto alloc = [&](size_t bytes) { char* q = p; p += (bytes + 255) & ~(size_t)255; return q; };
  float*  Wf0   = (float*)alloc(8192 * 4);
  float*  u1    = (float*)alloc(512 * 4);
  float*  u2    = (float*)alloc(512 * 4);
  float*  cbv   = (float*)alloc(64 * 4);
  float*  bf0   = (float*)alloc(64 * 4);
  float*  sbias = (float*)alloc(4 * 4);
  __half* G0h   = (__half*)alloc((size_t)V_N * 64 * 2);
  __half* Hbh   = (__half*)alloc((size_t)V_N * 64 * 2);
  __half* mbh   = (__half*)alloc((size_t)E_N * 64 * 2);
  float*  Af    = (float*)alloc((size_t)V_N * 64 * 4);
  float*  svx   = (float*)alloc((size_t)V_N * 4 * 4);
  float*  sex   = (float*)alloc((size_t)E_N * 4 * 4);
  float*  sE4   = (float*)alloc((size_t)NNZ_N * 4 * 4);
  float*  sV4   = (float*)alloc((size_t)NNZ_N * 4 * 4);
  float*  invE  = (float*)alloc(E_N * 4);
  float*  invV  = (float*)alloc(V_N * 4);
  int* zeroRegion = (int*)alloc((size_t)(2 * E_N + 2 * V_N) * 4);
  int* degE = zeroRegion;
  int* degV = degE + E_N;
  int* curE = degV + V_N;
  int* curV = curE + E_N;
  int* offE  = (int*)alloc(E_N * 4);
  int* offV  = (int*)alloc(V_N * 4);
  int* csrEv = (int*)alloc((size_t)NNZ_N * 4);
  int* csrVe = (int*)alloc((size_t)NNZ_N * 4);
  int* bsumE = (int*)alloc(64 * 4);
  int* bsumV = (int*)alloc(64 * 4);

  int nZero = 2 * E_N + 2 * V_N;
  int nchunkE = (E_N + CHUNK - 1) / CHUNK;   // 13
  int nchunkV = (V_N + CHUNK - 1) / CHUNK;   // 25
  int nbNode = (V_N + 63) / 64;              // 782
  int nbEdge = (E_N + 63) / 64;              // 391

  hipLaunchKernelGGL(k_zero, dim3((nZero + 255) / 256), dim3(256), 0, stream, zeroRegion, nZero);
  hipLaunchKernelGGL(k_fuse, dim3(128), dim3(64), 0, stream,
                     Wlin, blin, w1, w2, bs, W0, b0, Wf0, u1, u2, cbv, bf0, sbias);
  hipLaunchKernelGGL(k_degrees, dim3((NNZ_N + 255) / 256), dim3(256), 0, stream,
                     node_idx, edge_idx, degE, degV);
  hipLaunchKernelGGL(k_scanA, dim3(nchunkE + nchunkV), dim3(256), 0, stream,
                     degE, degV, offE, offV, bsumE, bsumV, nchunkE);
  hipLaunchKernelGGL(k_scanB, dim3(2), dim3(64), 0, stream, bsumE, bsumV, nchunkE, nchunkV);
  hipLaunchKernelGGL(k_scanC_inv, dim3(nchunkE + nchunkV), dim3(256), 0, stream,
                     offE, offV, bsumE, bsumV, degE, degV, invE, invV, nchunkE);
  hipLaunchKernelGGL(k_gemm_node, dim3(nbNode), dim3(256), 0, stream,
                     x, Wf0, u1, cbv, G0h, svx);
  hipLaunchKernelGGL(k_gemm_edge, dim3(nbEdge), dim3(256), 0, stream,
                     eattr, u2, sex);
  hipLaunchKernelGGL(k_fill_s, dim3((NNZ_N + 255) / 256), dim3(256), 0, stream,
                     node_idx, edge_idx, offE, offV, curE, curV, csrEv, csrVe,
                     sE4, sV4, svx, sex, sbias, invE, invV);
  hipLaunchKernelGGL(k_eagg, dim3((E_N + 3) / 4), dim3(256), 0, stream,
                     G0h, csrEv, sE4, offE, degE, mbh);
  hipLaunchKernelGGL(k_nagg, dim3((V_N + 3) / 4), dim3(256), 0, stream,
                     G0h, mbh, csrVe, sV4, offV, degV, bf0, 1, Hbh, (float*)nullptr);
  hipLaunchKernelGGL(k_eagg, dim3((E_N + 3) / 4), dim3(256), 0, stream,
                     Hbh, csrEv, sE4, offE, degE, mbh);
  hipLaunchKernelGGL(k_nagg, dim3((V_N + 3) / 4), dim3(256), 0, stream,
                     Hbh, mbh, csrVe, sV4, offV, degV, bf0, 0, (__half*)nullptr, Af);
  hipLaunchKernelGGL(k_final, dim3((V_N + 31) / 32), dim3(256), 0, stream, Af, W1, b1, W2, out);
}

// Round 9
// 293.438 us; speedup vs baseline: 1.4770x; 1.1077x over previous
//
#include <hip/hip_runtime.h>
#include <hip/hip_fp16.h>
#include <stdint.h>

#define V_N 50000
#define E_N 25000
#define NNZ_N 200000
#define CHUNK 2048
// F_IN=128, HID=256, D=4, H1=16, C=40

// ---------------- utility ----------------
__global__ __launch_bounds__(256) void k_zero(int* __restrict__ p, int n) {
  int i = blockIdx.x * 256 + threadIdx.x;
  if (i < n) p[i] = 0;
}

// ---------------- weight fusion (W0 LDS-staged) ----------------
__global__ __launch_bounds__(64) void k_fuse(
    const float* __restrict__ Wlin, const float* __restrict__ blin,
    const float* __restrict__ w1, const float* __restrict__ w2,
    const float* __restrict__ bs, const float* __restrict__ W0,
    const float* __restrict__ b0,
    float* __restrict__ Wf0, float* __restrict__ u1, float* __restrict__ u2,
    float* __restrict__ cb, float* __restrict__ bf0, float* __restrict__ sbias)
{
  __shared__ float row[1024];
  __shared__ float W0s[4096];
  int f = blockIdx.x;
  for (int t = threadIdx.x; t < 1024; t += 64) row[t] = Wlin[f * 1024 + t];
  for (int t = threadIdx.x; t < 4096; t += 64) W0s[t] = W0[t];
  __syncthreads();
  int j = threadIdx.x;
  int d = j >> 4, jj = j & 15;
  float acc = 0.f;
  for (int h = 0; h < 256; ++h) acc += row[d * 256 + h] * W0s[h * 16 + jj];
  Wf0[f * 64 + j] = acc;
  if (j < 4) {
    float a1 = 0.f, a2 = 0.f;
    for (int h = 0; h < 256; ++h) {
      a1 += row[j * 256 + h] * w1[h * 4 + j];
      a2 += row[j * 256 + h] * w2[h * 4 + j];
    }
    u1[f * 4 + j] = a1;
    u2[f * 4 + j] = a2;
  }
  if (f == 0) {
    float ab = 0.f;
    for (int h = 0; h < 256; ++h) ab += blin[d * 256 + h] * W0s[h * 16 + jj];
    cb[j] = ab;
    bf0[j] = b0[jj];
    if (j < 4) {
      float sb = bs[j];
      for (int h = 0; h < 256; ++h) sb += blin[j * 256 + h] * (w1[h * 4 + j] + w2[h * 4 + j]);
      sbias[j] = sb;
    }
  }
}

// ---------------- degrees ----------------
__global__ __launch_bounds__(256) void k_degrees(
    const int* __restrict__ node_idx, const int* __restrict__ edge_idx,
    int* __restrict__ degE, int* __restrict__ degV)
{
  int i = blockIdx.x * 256 + threadIdx.x;
  if (i < NNZ_N) {
    atomicAdd(&degE[edge_idx[i]], 1);
    atomicAdd(&degV[node_idx[i]], 1);
  }
}

// ---------------- scans (exclusive) ----------------
__global__ __launch_bounds__(256) void k_scanA(
    const int* __restrict__ degE, const int* __restrict__ degV,
    int* __restrict__ offE, int* __restrict__ offV,
    int* __restrict__ bsumE, int* __restrict__ bsumV, int nchunkE)
{
  bool isE = (int)blockIdx.x < nchunkE;
  const int* deg = isE ? degE : degV;
  int* off = isE ? offE : offV;
  int* bsum = isE ? bsumE : bsumV;
  int n = isE ? E_N : V_N;
  int chunk = isE ? blockIdx.x : (blockIdx.x - nchunkE);
  int base = chunk * CHUNK;
  int tid = threadIdx.x;
  int vals[8];
  int tsum = 0;
  for (int it = 0; it < 8; ++it) {
    int idx = base + tid * 8 + it;
    int v = (idx < n) ? deg[idx] : 0;
    vals[it] = tsum;
    tsum += v;
  }
  __shared__ int sA[256], sB[256];
  sA[tid] = tsum;
  __syncthreads();
  int* src = sA; int* dst = sB;
  for (int sh = 1; sh < 256; sh <<= 1) {
    dst[tid] = src[tid] + (tid >= sh ? src[tid - sh] : 0);
    __syncthreads();
    int* t = src; src = dst; dst = t;
  }
  int excl = src[tid] - tsum;
  for (int it = 0; it < 8; ++it) {
    int idx = base + tid * 8 + it;
    if (idx < n) off[idx] = excl + vals[it];
  }
  if (tid == 255) bsum[chunk] = src[255];
}

__global__ __launch_bounds__(64) void k_scanB(
    int* __restrict__ bsumE, int* __restrict__ bsumV, int nchunkE, int nchunkV)
{
  int* b = (blockIdx.x == 0) ? bsumE : bsumV;
  int n = (blockIdx.x == 0) ? nchunkE : nchunkV;
  int tid = threadIdx.x;
  int v = (tid < n) ? b[tid] : 0;
  int s = v;
  for (int sh = 1; sh < 64; sh <<= 1) {
    int o = __shfl_up(s, sh);
    if (tid >= sh) s += o;
  }
  if (tid < n) b[tid] = s - v;
}

__global__ __launch_bounds__(256) void k_scanC_inv(
    int* __restrict__ offE, int* __restrict__ offV,
    const int* __restrict__ bsumE, const int* __restrict__ bsumV,
    const int* __restrict__ degE, const int* __restrict__ degV,
    float* __restrict__ invE, float* __restrict__ invV, int nchunkE)
{
  bool isE = (int)blockIdx.x < nchunkE;
  int* off = isE ? offE : offV;
  const int* bsum = isE ? bsumE : bsumV;
  const int* deg = isE ? degE : degV;
  float* inv = isE ? invE : invV;
  int n = isE ? E_N : V_N;
  int chunk = isE ? blockIdx.x : (blockIdx.x - nchunkE);
  int base = chunk * CHUNK;
  int add = bsum[chunk];
  for (int it = 0; it < 8; ++it) {
    int idx = base + threadIdx.x * 8 + it;
    if (idx < n) {
      off[idx] += add;
      int dg = deg[idx];
      inv[idx] = dg > 0 ? 1.0f / (float)dg : 0.0f;
    }
  }
}

// ---------------- node GEMM: G0h = fp16(x @ Wf0 + cb) [V,64], svx = x @ u1 [V,4] ----------------
__global__ __launch_bounds__(256) void k_gemm_node(
    const float* __restrict__ x, const float* __restrict__ Wf0,
    const float* __restrict__ u1, const float* __restrict__ cb,
    __half* __restrict__ G0h, float* __restrict__ svx)
{
  __shared__ float Xt[64 * 132];   // 33792 B
  __shared__ float us[512];        // u1 [128][4]
  int tid = threadIdx.x;
  int row0 = blockIdx.x * 64;
  #pragma unroll
  for (int it = 0; it < 8; ++it) {
    int fi = it * 1024 + tid * 4;
    int r = fi >> 7, c = fi & 127;
    float4 val = make_float4(0.f, 0.f, 0.f, 0.f);
    int gr = row0 + r;
    if (gr < V_N) val = *(const float4*)(x + (size_t)gr * 128 + c);
    *(float4*)&Xt[r * 132 + c] = val;
  }
  for (int k2 = tid; k2 < 512; k2 += 256) us[k2] = u1[k2];
  int ty = tid >> 4, tx = tid & 15;
  float4 cbr = *(const float4*)(cb + tx * 4);
  __syncthreads();

  float acc[4][4];
  #pragma unroll
  for (int i = 0; i < 4; ++i) {
    acc[i][0] = cbr.x; acc[i][1] = cbr.y; acc[i][2] = cbr.z; acc[i][3] = cbr.w;
  }
  #pragma unroll 2
  for (int k0 = 0; k0 < 128; k0 += 4) {
    float A_[4][4], W_[4][4];
    #pragma unroll
    for (int kk = 0; kk < 4; ++kk)
      *(float4*)&W_[kk][0] = *(const float4*)(Wf0 + (size_t)(k0 + kk) * 64 + tx * 4);
    #pragma unroll
    for (int i = 0; i < 4; ++i)
      *(float4*)&A_[i][0] = *(const float4*)&Xt[(ty * 4 + i) * 132 + k0];
    #pragma unroll
    for (int i = 0; i < 4; ++i)
      #pragma unroll
      for (int kk = 0; kk < 4; ++kk)
        #pragma unroll
        for (int j = 0; j < 4; ++j)
          acc[i][j] += A_[i][kk] * W_[kk][j];
  }
  #pragma unroll
  for (int i = 0; i < 4; ++i) {
    int gr = row0 + ty * 4 + i;
    if (gr < V_N) {
      __half2* dst = (__half2*)(G0h + (size_t)gr * 64 + tx * 4);
      dst[0] = __floats2half2_rn(acc[i][0], acc[i][1]);
      dst[1] = __floats2half2_rn(acc[i][2], acc[i][3]);
    }
  }
  int rs = tid >> 2, dS = tid & 3;
  float a2 = 0.f;
  for (int k = 0; k < 128; ++k)
    a2 += Xt[rs * 132 + k] * us[k * 4 + dS];
  int gr = row0 + rs;
  if (gr < V_N) svx[gr * 4 + dS] = a2;
}

// ---------------- edge GEMM: sex = eattr @ u2 [E,4] (slim) ----------------
__global__ __launch_bounds__(256) void k_gemm_edge(
    const float* __restrict__ eattr, const float* __restrict__ u2,
    float* __restrict__ sex)
{
  __shared__ float Xt[64 * 132];
  __shared__ float us[512];
  int tid = threadIdx.x;
  int row0 = blockIdx.x * 64;
  #pragma unroll
  for (int it = 0; it < 8; ++it) {
    int fi = it * 1024 + tid * 4;
    int r = fi >> 7, c = fi & 127;
    float4 val = make_float4(0.f, 0.f, 0.f, 0.f);
    int gr = row0 + r;
    if (gr < E_N) val = *(const float4*)(eattr + (size_t)gr * 128 + c);
    *(float4*)&Xt[r * 132 + c] = val;
  }
  for (int k2 = tid; k2 < 512; k2 += 256) us[k2] = u2[k2];
  __syncthreads();
  int rs = tid >> 2, dS = tid & 3;
  float a2 = 0.f;
  for (int k = 0; k < 128; ++k)
    a2 += Xt[rs * 132 + k] * us[k * 4 + dS];
  int gr = row0 + rs;
  if (gr < E_N) sex[gr * 4 + dS] = a2;
}

// ---------------- CSR fill + permuted s payloads (inv pre-folded) ----------------
__global__ __launch_bounds__(256) void k_fill_s(
    const int* __restrict__ node_idx, const int* __restrict__ edge_idx,
    const int* __restrict__ offE, const int* __restrict__ offV,
    int* __restrict__ curE, int* __restrict__ curV,
    int* __restrict__ csrEv, int* __restrict__ csrVe,
    float* __restrict__ sE4, float* __restrict__ sV4,
    const float* __restrict__ svx, const float* __restrict__ sex,
    const float* __restrict__ sbias,
    const float* __restrict__ invE, const float* __restrict__ invV)
{
  int i = blockIdx.x * 256 + threadIdx.x;
  if (i >= NNZ_N) return;
  int v = node_idx[i], e = edge_idx[i];
  float4 a = *(const float4*)(svx + (size_t)v * 4);
  float4 b = *(const float4*)(sex + (size_t)e * 4);
  float4 sb = *(const float4*)(sbias);
  float4 r;
  r.x = tanhf(a.x + b.x + sb.x);
  r.y = tanhf(a.y + b.y + sb.y);
  r.z = tanhf(a.z + b.z + sb.z);
  r.w = tanhf(a.w + b.w + sb.w);
  float ie = invE[e], iv = invV[v];
  int pe = atomicAdd(&curE[e], 1);
  int slotE = offE[e] + pe;
  csrEv[slotE] = v;
  float4 re = make_float4(r.x * ie, r.y * ie, r.z * ie, r.w * ie);
  *(float4*)(sE4 + (size_t)slotE * 4) = re;
  int pv = atomicAdd(&curV[v], 1);
  int slotV = offV[v] + pv;
  csrVe[slotV] = e;
  float4 rv = make_float4(r.x * iv, r.y * iv, r.z * iv, r.w * iv);
  *(float4*)(sV4 + (size_t)slotV * 4) = rv;
}

// ---------------- sheaf Laplacian stages: quarter-wave rows, 4 gathers in flight ----
// wave = 1 segment; 4 quarter-waves process 4 incidences concurrently.
// lane: qw = lane>>4 (incidence t=q+qw), L16 = lane&15 (ch = L16*4..+3, d = L16>>2).
__global__ __launch_bounds__(256) void k_eagg(
    const __half* __restrict__ Hin, const int* __restrict__ csrEv,
    const float* __restrict__ sE4,
    const int* __restrict__ offE, const int* __restrict__ degE,
    __half* __restrict__ m)
{
  int g = threadIdx.x >> 6, lane = threadIdx.x & 63;
  int e = blockIdx.x * 4 + g;
  if (e >= E_N) return;
  int o0 = offE[e], dg = degE[e];
  int qw = lane >> 4, L16 = lane & 15;
  int d = L16 >> 2;
  float4 acc = make_float4(0.f, 0.f, 0.f, 0.f);
  for (int base = 0; base < dg; base += 16) {
    int idx = base + L16;
    int vv = (idx < dg) ? csrEv[o0 + idx] : 0;
    int sidx = base * 4 + lane;
    float ss = (sidx < dg * 4) ? sE4[(size_t)o0 * 4 + sidx] : 0.f;
    int lim = min(16, dg - base);
    #pragma unroll 2
    for (int q = 0; q < lim; q += 4) {
      int tloc = q + qw;
      int v = __shfl(vv, tloc);
      float sv = __shfl(ss, tloc * 4 + d);
      if (tloc < lim) {
        uint2 raw = *(const uint2*)(Hin + (size_t)v * 64 + L16 * 4);
        __half2 ha = *reinterpret_cast<__half2*>(&raw.x);
        __half2 hb = *reinterpret_cast<__half2*>(&raw.y);
        float2 fa = __half22float2(ha), fb = __half22float2(hb);
        acc.x += sv * fa.x; acc.y += sv * fa.y;
        acc.z += sv * fb.x; acc.w += sv * fb.y;
      }
    }
  }
  acc.x += __shfl_xor(acc.x, 16); acc.y += __shfl_xor(acc.y, 16);
  acc.z += __shfl_xor(acc.z, 16); acc.w += __shfl_xor(acc.w, 16);
  acc.x += __shfl_xor(acc.x, 32); acc.y += __shfl_xor(acc.y, 32);
  acc.z += __shfl_xor(acc.z, 32); acc.w += __shfl_xor(acc.w, 32);
  if (qw == 0) {
    __half2 oa = __floats2half2_rn(acc.x, acc.y);
    __half2 ob = __floats2half2_rn(acc.z, acc.w);
    uint2 o; o.x = *(unsigned int*)&oa; o.y = *(unsigned int*)&ob;
    *(uint2*)(m + (size_t)e * 64 + L16 * 4) = o;   // invE folded into sE4
  }
}

__global__ __launch_bounds__(256) void k_nagg(
    const __half* __restrict__ base_, const __half* __restrict__ m,
    const int* __restrict__ csrVe, const float* __restrict__ sV4,
    const int* __restrict__ offV, const int* __restrict__ degV,
    const float* __restrict__ bf0, int doRelu,
    __half* __restrict__ outH, float* __restrict__ outF)
{
  int g = threadIdx.x >> 6, lane = threadIdx.x & 63;
  int v = blockIdx.x * 4 + g;
  if (v >= V_N) return;
  int o0 = offV[v], dg = degV[v];
  int qw = lane >> 4, L16 = lane & 15;
  int d = L16 >> 2;
  float4 acc = make_float4(0.f, 0.f, 0.f, 0.f);
  for (int base = 0; base < dg; base += 16) {
    int idx = base + L16;
    int ee = (idx < dg) ? csrVe[o0 + idx] : 0;
    int sidx = base * 4 + lane;
    float ss = (sidx < dg * 4) ? sV4[(size_t)o0 * 4 + sidx] : 0.f;
    int lim = min(16, dg - base);
    #pragma unroll 2
    for (int q = 0; q < lim; q += 4) {
      int tloc = q + qw;
      int e = __shfl(ee, tloc);
      float sv = __shfl(ss, tloc * 4 + d);
      if (tloc < lim) {
        uint2 raw = *(const uint2*)(m + (size_t)e * 64 + L16 * 4);
        __half2 ha = *reinterpret_cast<__half2*>(&raw.x);
        __half2 hb = *reinterpret_cast<__half2*>(&raw.y);
        float2 fa = __half22float2(ha), fb = __half22float2(hb);
        acc.x += sv * fa.x; acc.y += sv * fa.y;
        acc.z += sv * fb.x; acc.w += sv * fb.y;
      }
    }
  }
  acc.x += __shfl_xor(acc.x, 16); acc.y += __shfl_xor(acc.y, 16);
  acc.z += __shfl_xor(acc.z, 16); acc.w += __shfl_xor(acc.w, 16);
  acc.x += __shfl_xor(acc.x, 32); acc.y += __shfl_xor(acc.y, 32);
  acc.z += __shfl_xor(acc.z, 32); acc.w += __shfl_xor(acc.w, 32);
  if (qw == 0) {
    uint2 braw = *(const uint2*)(base_ + (size_t)v * 64 + L16 * 4);
    __half2 b0h = *reinterpret_cast<__half2*>(&braw.x);
    __half2 b1h = *reinterpret_cast<__half2*>(&braw.y);
    float2 bfa = __half22float2(b0h), bfb = __half22float2(b1h);
    float r0 = bfa.x - acc.x, r1 = bfa.y - acc.y;
    float r2 = bfb.x - acc.z, r3 = bfb.y - acc.w;   // invV folded into sV4
    if (doRelu) {
      float4 bf = *(const float4*)(bf0 + L16 * 4);
      r0 = fmaxf(r0 + bf.x, 0.f); r1 = fmaxf(r1 + bf.y, 0.f);
      r2 = fmaxf(r2 + bf.z, 0.f); r3 = fmaxf(r3 + bf.w, 0.f);
      __half2 oa = __floats2half2_rn(r0, r1);
      __half2 ob = __floats2half2_rn(r2, r3);
      uint2 o; o.x = *(unsigned int*)&oa; o.y = *(unsigned int*)&ob;
      *(uint2*)(outH + (size_t)v * 64 + L16 * 4) = o;
    } else {
      *(float4*)(outF + (size_t)v * 64 + L16 * 4) = make_float4(r0, r1, r2, r3);
    }
  }
}

// ---------------- fused tail: register-tiled, 32 rows/block ----------------
__global__ __launch_bounds__(256) void k_final(
    const float* __restrict__ A, const float* __restrict__ W1, const float* __restrict__ b1,
    const float* __restrict__ W2, float* __restrict__ out)
{
  __shared__ float W2s[160 * 40];
  __shared__ float t[32 * 164];
  __shared__ float W1s[640];
  __shared__ float b1s[40];
  int tid = threadIdx.x;
  int v0 = blockIdx.x * 32;

  for (int k = tid; k < 1600; k += 256) ((float4*)W2s)[k] = ((const float4*)W2)[k];
  for (int k = tid; k < 640; k += 256) W1s[k] = W1[k];
  if (tid < 40) b1s[tid] = b1[tid];
  __syncthreads();

  if (tid < 160) {
    int rg = tid / 20, cg = tid % 20;
    int r0 = rg * 4;
    int j0 = cg * 8;
    int d = cg / 5;
    int jloc = j0 - d * 40;
    float a[4][16];
    #pragma unroll
    for (int i = 0; i < 4; ++i) {
      int gr = v0 + r0 + i;
      #pragma unroll
      for (int c4 = 0; c4 < 4; ++c4) {
        float4 val = make_float4(0.f, 0.f, 0.f, 0.f);
        if (gr < V_N) val = *(const float4*)(A + (size_t)gr * 64 + d * 16 + c4 * 4);
        *(float4*)&a[i][c4 * 4] = val;
      }
    }
    float acc1[4][8];
    #pragma unroll
    for (int i = 0; i < 4; ++i)
      #pragma unroll
      for (int jj = 0; jj < 8; ++jj) acc1[i][jj] = b1s[jloc + jj];
    #pragma unroll
    for (int c = 0; c < 16; ++c) {
      float w[8];
      *(float4*)&w[0] = *(const float4*)&W1s[c * 40 + jloc];
      *(float4*)&w[4] = *(const float4*)&W1s[c * 40 + jloc + 4];
      #pragma unroll
      for (int i = 0; i < 4; ++i)
        #pragma unroll
        for (int jj = 0; jj < 8; ++jj)
          acc1[i][jj] += a[i][c] * w[jj];
    }
    #pragma unroll
    for (int i = 0; i < 4; ++i) {
      float4 lo = make_float4(fmaxf(acc1[i][0], 0.f), fmaxf(acc1[i][1], 0.f),
                              fmaxf(acc1[i][2], 0.f), fmaxf(acc1[i][3], 0.f));
      float4 hi = make_float4(fmaxf(acc1[i][4], 0.f), fmaxf(acc1[i][5], 0.f),
                              fmaxf(acc1[i][6], 0.f), fmaxf(acc1[i][7], 0.f));
      *(float4*)&t[(r0 + i) * 164 + j0] = lo;
      *(float4*)&t[(r0 + i) * 164 + j0 + 4] = hi;
    }
  }
  __syncthreads();

  if (tid < 160) {
    int rg2 = tid / 10, cg2 = tid % 10;
    float acc2[2][4] = {{0.f, 0.f, 0.f, 0.f}, {0.f, 0.f, 0.f, 0.f}};
    for (int k0 = 0; k0 < 160; k0 += 4) {
      float a0[4], a1[4], w[4][4];
      *(float4*)a0 = *(const float4*)&t[(rg2 * 2 + 0) * 164 + k0];
      *(float4*)a1 = *(const float4*)&t[(rg2 * 2 + 1) * 164 + k0];
      #pragma unroll
      for (int kk = 0; kk < 4; ++kk)
        *(float4*)&w[kk][0] = *(const float4*)&W2s[(k0 + kk) * 40 + cg2 * 4];
      #pragma unroll
      for (int kk = 0; kk < 4; ++kk)
        #pragma unroll
        for (int j = 0; j < 4; ++j) {
          acc2[0][j] += a0[kk] * w[kk][j];
          acc2[1][j] += a1[kk] * w[kk][j];
        }
    }
    #pragma unroll
    for (int i = 0; i < 2; ++i) {
      int gr = v0 + rg2 * 2 + i;
      if (gr < V_N)
        *(float4*)(out + (size_t)gr * 40 + cg2 * 4) =
            make_float4(acc2[i][0], acc2[i][1], acc2[i][2], acc2[i][3]);
    }
  }
}

extern "C" void kernel_launch(void* const* d_in, const int* in_sizes, int n_in,
                              void* d_out, int out_size, void* d_ws, size_t ws_size,
                              hipStream_t stream) {
  (void)in_sizes; (void)n_in; (void)out_size; (void)ws_size;
  const float* x = (const float*)d_in[0];
  const float* eattr = (const float*)d_in[1];
  const int* node_idx = (const int*)d_in[2];
  const int* edge_idx = (const int*)d_in[3];
  const float* Wlin = (const float*)d_in[4];
  const float* blin = (const float*)d_in[5];
  const float* w1 = (const float*)d_in[6];
  const float* w2 = (const float*)d_in[7];
  const float* bs = (const float*)d_in[8];
  const float* W0 = (const float*)d_in[9];
  const float* b0 = (const float*)d_in[10];
  const float* W1 = (const float*)d_in[11];
  const float* b1 = (const float*)d_in[12];
  const float* W2 = (const float*)d_in[13];
  float* out = (float*)d_out;

  char* p = (char*)d_ws;
  auto alloc = [&](size_t bytes) { char* q = p; p += (bytes + 255) & ~(size_t)255; return q; };
  float*  Wf0   = (float*)alloc(8192 * 4);
  float*  u1    = (float*)alloc(512 * 4);
  float*  u2    = (float*)alloc(512 * 4);
  float*  cbv   = (float*)alloc(64 * 4);
  float*  bf0   = (float*)alloc(64 * 4);
  float*  sbias = (float*)alloc(4 * 4);
  __half* G0h   = (__half*)alloc((size_t)V_N * 64 * 2);
  __half* Hbh   = (__half*)alloc((size_t)V_N * 64 * 2);
  __half* mbh   = (__half*)alloc((size_t)E_N * 64 * 2);
  float*  Af    = (float*)alloc((size_t)V_N * 64 * 4);
  float*  svx   = (float*)alloc((size_t)V_N * 4 * 4);
  float*  sex   = (float*)alloc((size_t)E_N * 4 * 4);
  float*  sE4   = (float*)alloc((size_t)NNZ_N * 4 * 4);
  float*  sV4   = (float*)alloc((size_t)NNZ_N * 4 * 4);
  float*  invE  = (float*)alloc(E_N * 4);
  float*  invV  = (float*)alloc(V_N * 4);
  int* zeroRegion = (int*)alloc((size_t)(2 * E_N + 2 * V_N) * 4);
  int* degE = zeroRegion;
  int* degV = degE + E_N;
  int* curE = degV + V_N;
  int* curV = curE + E_N;
  int* offE  = (int*)alloc(E_N * 4);
  int* offV  = (int*)alloc(V_N * 4);
  int* csrEv = (int*)alloc((size_t)NNZ_N * 4);
  int* csrVe = (int*)alloc((size_t)NNZ_N * 4);
  int* bsumE = (int*)alloc(64 * 4);
  int* bsumV = (int*)alloc(64 * 4);

  int nZero = 2 * E_N + 2 * V_N;
  int nchunkE = (E_N + CHUNK - 1) / CHUNK;   // 13
  int nchunkV = (V_N + CHUNK - 1) / CHUNK;   // 25
  int nbNode = (V_N + 63) / 64;              // 782
  int nbEdge = (E_N + 63) / 64;              // 391

  hipLaunchKernelGGL(k_zero, dim3((nZero + 255) / 256), dim3(256), 0, stream, zeroRegion, nZero);
  hipLaunchKernelGGL(k_fuse, dim3(128), dim3(64), 0, stream,
                     Wlin, blin, w1, w2, bs, W0, b0, Wf0, u1, u2, cbv, bf0, sbias);
  hipLaunchKernelGGL(k_degrees, dim3((NNZ_N + 255) / 256), dim3(256), 0, stream,
                     node_idx, edge_idx, degE, degV);
  hipLaunchKernelGGL(k_scanA, dim3(nchunkE + nchunkV), dim3(256), 0, stream,
                     degE, degV, offE, offV, bsumE, bsumV, nchunkE);
  hipLaunchKernelGGL(k_scanB, dim3(2), dim3(64), 0, stream, bsumE, bsumV, nchunkE, nchunkV);
  hipLaunchKernelGGL(k_scanC_inv, dim3(nchunkE + nchunkV), dim3(256), 0, stream,
                     offE, offV, bsumE, bsumV, degE, degV, invE, invV, nchunkE);
  hipLaunchKernelGGL(k_gemm_node, dim3(nbNode), dim3(256), 0, stream,
                     x, Wf0, u1, cbv, G0h, svx);
  hipLaunchKernelGGL(k_gemm_edge, dim3(nbEdge), dim3(256), 0, stream,
                     eattr, u2, sex);
  hipLaunchKernelGGL(k_fill_s, dim3((NNZ_N + 255) / 256), dim3(256), 0, stream,
                     node_idx, edge_idx, offE, offV, curE, curV, csrEv, csrVe,
                     sE4, sV4, svx, sex, sbias, invE, invV);
  hipLaunchKernelGGL(k_eagg, dim3((E_N + 3) / 4), dim3(256), 0, stream,
                     G0h, csrEv, sE4, offE, degE, mbh);
  hipLaunchKernelGGL(k_nagg, dim3((V_N + 3) / 4), dim3(256), 0, stream,
                     G0h, mbh, csrVe, sV4, offV, degV, bf0, 1, Hbh, (float*)nullptr);
  hipLaunchKernelGGL(k_eagg, dim3((E_N + 3) / 4), dim3(256), 0, stream,
                     Hbh, csrEv, sE4, offE, degE, mbh);
  hipLaunchKernelGGL(k_nagg, dim3((V_N + 3) / 4), dim3(256), 0, stream,
                     Hbh, mbh, csrVe, sV4, offV, degV, bf0, 0, (__half*)nullptr, Af);
  hipLaunchKernelGGL(k_final, dim3((V_N + 31) / 32), dim3(256), 0, stream, Af, W1, b1, W2, out);
}

// Round 11
// 284.119 us; speedup vs baseline: 1.5254x; 1.0328x over previous
//
#include <hip/hip_runtime.h>
#include <hip/hip_fp16.h>
#include <stdint.h>

#define V_N 50000
#define E_N 25000
#define NNZ_N 200000
#define CHUNK 2048
// F_IN=128, HID=256, D=4, H1=16, C=40

// ---------------- utility ----------------
__global__ __launch_bounds__(256) void k_zero(int* __restrict__ p, int n) {
  int i = blockIdx.x * 256 + threadIdx.x;
  if (i < n) p[i] = 0;
}

// ---------------- weight fusion (W0 LDS-staged) ----------------
__global__ __launch_bounds__(64) void k_fuse(
    const float* __restrict__ Wlin, const float* __restrict__ blin,
    const float* __restrict__ w1, const float* __restrict__ w2,
    const float* __restrict__ bs, const float* __restrict__ W0,
    const float* __restrict__ b0,
    float* __restrict__ Wf0, float* __restrict__ u1, float* __restrict__ u2,
    float* __restrict__ cb, float* __restrict__ bf0, float* __restrict__ sbias)
{
  __shared__ float row[1024];
  __shared__ float W0s[4096];
  int f = blockIdx.x;
  for (int t = threadIdx.x; t < 1024; t += 64) row[t] = Wlin[f * 1024 + t];
  for (int t = threadIdx.x; t < 4096; t += 64) W0s[t] = W0[t];
  __syncthreads();
  int j = threadIdx.x;
  int d = j >> 4, jj = j & 15;
  float acc = 0.f;
  for (int h = 0; h < 256; ++h) acc += row[d * 256 + h] * W0s[h * 16 + jj];
  Wf0[f * 64 + j] = acc;
  if (j < 4) {
    float a1 = 0.f, a2 = 0.f;
    for (int h = 0; h < 256; ++h) {
      a1 += row[j * 256 + h] * w1[h * 4 + j];
      a2 += row[j * 256 + h] * w2[h * 4 + j];
    }
    u1[f * 4 + j] = a1;
    u2[f * 4 + j] = a2;
  }
  if (f == 0) {
    float ab = 0.f;
    for (int h = 0; h < 256; ++h) ab += blin[d * 256 + h] * W0s[h * 16 + jj];
    cb[j] = ab;
    bf0[j] = b0[jj];
    if (j < 4) {
      float sb = bs[j];
      for (int h = 0; h < 256; ++h) sb += blin[j * 256 + h] * (w1[h * 4 + j] + w2[h * 4 + j]);
      sbias[j] = sb;
    }
  }
}

// ---------------- degrees ----------------
__global__ __launch_bounds__(256) void k_degrees(
    const int* __restrict__ node_idx, const int* __restrict__ edge_idx,
    int* __restrict__ degE, int* __restrict__ degV)
{
  int i = blockIdx.x * 256 + threadIdx.x;
  if (i < NNZ_N) {
    atomicAdd(&degE[edge_idx[i]], 1);
    atomicAdd(&degV[node_idx[i]], 1);
  }
}

// ---------------- scans (exclusive) ----------------
__global__ __launch_bounds__(256) void k_scanA(
    const int* __restrict__ degE, const int* __restrict__ degV,
    int* __restrict__ offE, int* __restrict__ offV,
    int* __restrict__ bsumE, int* __restrict__ bsumV, int nchunkE)
{
  bool isE = (int)blockIdx.x < nchunkE;
  const int* deg = isE ? degE : degV;
  int* off = isE ? offE : offV;
  int* bsum = isE ? bsumE : bsumV;
  int n = isE ? E_N : V_N;
  int chunk = isE ? blockIdx.x : (blockIdx.x - nchunkE);
  int base = chunk * CHUNK;
  int tid = threadIdx.x;
  int vals[8];
  int tsum = 0;
  for (int it = 0; it < 8; ++it) {
    int idx = base + tid * 8 + it;
    int v = (idx < n) ? deg[idx] : 0;
    vals[it] = tsum;
    tsum += v;
  }
  __shared__ int sA[256], sB[256];
  sA[tid] = tsum;
  __syncthreads();
  int* src = sA; int* dst = sB;
  for (int sh = 1; sh < 256; sh <<= 1) {
    dst[tid] = src[tid] + (tid >= sh ? src[tid - sh] : 0);
    __syncthreads();
    int* t = src; src = dst; dst = t;
  }
  int excl = src[tid] - tsum;
  for (int it = 0; it < 8; ++it) {
    int idx = base + tid * 8 + it;
    if (idx < n) off[idx] = excl + vals[it];
  }
  if (tid == 255) bsum[chunk] = src[255];
}

__global__ __launch_bounds__(64) void k_scanB(
    int* __restrict__ bsumE, int* __restrict__ bsumV, int nchunkE, int nchunkV)
{
  int* b = (blockIdx.x == 0) ? bsumE : bsumV;
  int n = (blockIdx.x == 0) ? nchunkE : nchunkV;
  int tid = threadIdx.x;
  int v = (tid < n) ? b[tid] : 0;
  int s = v;
  for (int sh = 1; sh < 64; sh <<= 1) {
    int o = __shfl_up(s, sh);
    if (tid >= sh) s += o;
  }
  if (tid < n) b[tid] = s - v;
}

__global__ __launch_bounds__(256) void k_scanC_inv(
    int* __restrict__ offE, int* __restrict__ offV,
    const int* __restrict__ bsumE, const int* __restrict__ bsumV,
    const int* __restrict__ degE, const int* __restrict__ degV,
    float* __restrict__ invE, float* __restrict__ invV, int nchunkE)
{
  bool isE = (int)blockIdx.x < nchunkE;
  int* off = isE ? offE : offV;
  const int* bsum = isE ? bsumE : bsumV;
  const int* deg = isE ? degE : degV;
  float* inv = isE ? invE : invV;
  int n = isE ? E_N : V_N;
  int chunk = isE ? blockIdx.x : (blockIdx.x - nchunkE);
  int base = chunk * CHUNK;
  int add = bsum[chunk];
  for (int it = 0; it < 8; ++it) {
    int idx = base + threadIdx.x * 8 + it;
    if (idx < n) {
      off[idx] += add;
      int dg = deg[idx];
      inv[idx] = dg > 0 ? 1.0f / (float)dg : 0.0f;
    }
  }
}

// ---------------- node GEMM: G0h = fp16(x @ Wf0 + cb) [V,64], svx = x @ u1 [V,4] ----------------
__global__ __launch_bounds__(256) void k_gemm_node(
    const float* __restrict__ x, const float* __restrict__ Wf0,
    const float* __restrict__ u1, const float* __restrict__ cb,
    __half* __restrict__ G0h, float* __restrict__ svx)
{
  __shared__ float Xt[64 * 132];   // 33792 B
  __shared__ float us[512];        // u1 [128][4]
  int tid = threadIdx.x;
  int row0 = blockIdx.x * 64;
  #pragma unroll
  for (int it = 0; it < 8; ++it) {
    int fi = it * 1024 + tid * 4;
    int r = fi >> 7, c = fi & 127;
    float4 val = make_float4(0.f, 0.f, 0.f, 0.f);
    int gr = row0 + r;
    if (gr < V_N) val = *(const float4*)(x + (size_t)gr * 128 + c);
    *(float4*)&Xt[r * 132 + c] = val;
  }
  for (int k2 = tid; k2 < 512; k2 += 256) us[k2] = u1[k2];
  int ty = tid >> 4, tx = tid & 15;
  float4 cbr = *(const float4*)(cb + tx * 4);
  __syncthreads();

  float acc[4][4];
  #pragma unroll
  for (int i = 0; i < 4; ++i) {
    acc[i][0] = cbr.x; acc[i][1] = cbr.y; acc[i][2] = cbr.z; acc[i][3] = cbr.w;
  }
  #pragma unroll 2
  for (int k0 = 0; k0 < 128; k0 += 4) {
    float A_[4][4], W_[4][4];
    #pragma unroll
    for (int kk = 0; kk < 4; ++kk)
      *(float4*)&W_[kk][0] = *(const float4*)(Wf0 + (size_t)(k0 + kk) * 64 + tx * 4);
    #pragma unroll
    for (int i = 0; i < 4; ++i)
      *(float4*)&A_[i][0] = *(const float4*)&Xt[(ty * 4 + i) * 132 + k0];
    #pragma unroll
    for (int i = 0; i < 4; ++i)
      #pragma unroll
      for (int kk = 0; kk < 4; ++kk)
        #pragma unroll
        for (int j = 0; j < 4; ++j)
          acc[i][j] += A_[i][kk] * W_[kk][j];
  }
  #pragma unroll
  for (int i = 0; i < 4; ++i) {
    int gr = row0 + ty * 4 + i;
    if (gr < V_N) {
      __half2* dst = (__half2*)(G0h + (size_t)gr * 64 + tx * 4);
      dst[0] = __floats2half2_rn(acc[i][0], acc[i][1]);
      dst[1] = __floats2half2_rn(acc[i][2], acc[i][3]);
    }
  }
  int rs = tid >> 2, dS = tid & 3;
  float a2 = 0.f;
  for (int k = 0; k < 128; ++k)
    a2 += Xt[rs * 132 + k] * us[k * 4 + dS];
  int gr = row0 + rs;
  if (gr < V_N) svx[gr * 4 + dS] = a2;
}

// ---------------- edge GEMM: sex = eattr @ u2 [E,4] (slim) ----------------
__global__ __launch_bounds__(256) void k_gemm_edge(
    const float* __restrict__ eattr, const float* __restrict__ u2,
    float* __restrict__ sex)
{
  __shared__ float Xt[64 * 132];
  __shared__ float us[512];
  int tid = threadIdx.x;
  int row0 = blockIdx.x * 64;
  #pragma unroll
  for (int it = 0; it < 8; ++it) {
    int fi = it * 1024 + tid * 4;
    int r = fi >> 7, c = fi & 127;
    float4 val = make_float4(0.f, 0.f, 0.f, 0.f);
    int gr = row0 + r;
    if (gr < E_N) val = *(const float4*)(eattr + (size_t)gr * 128 + c);
    *(float4*)&Xt[r * 132 + c] = val;
  }
  for (int k2 = tid; k2 < 512; k2 += 256) us[k2] = u2[k2];
  __syncthreads();
  int rs = tid >> 2, dS = tid & 3;
  float a2 = 0.f;
  for (int k = 0; k < 128; ++k)
    a2 += Xt[rs * 132 + k] * us[k * 4 + dS];
  int gr = row0 + rs;
  if (gr < E_N) sex[gr * 4 + dS] = a2;
}

// ---------------- CSR fill + permuted s payloads (inv pre-folded) ----------------
__global__ __launch_bounds__(256) void k_fill_s(
    const int* __restrict__ node_idx, const int* __restrict__ edge_idx,
    const int* __restrict__ offE, const int* __restrict__ offV,
    int* __restrict__ curE, int* __restrict__ curV,
    int* __restrict__ csrEv, int* __restrict__ csrVe,
    float* __restrict__ sE4, float* __restrict__ sV4,
    const float* __restrict__ svx, const float* __restrict__ sex,
    const float* __restrict__ sbias,
    const float* __restrict__ invE, const float* __restrict__ invV)
{
  int i = blockIdx.x * 256 + threadIdx.x;
  if (i >= NNZ_N) return;
  int v = node_idx[i], e = edge_idx[i];
  float4 a = *(const float4*)(svx + (size_t)v * 4);
  float4 b = *(const float4*)(sex + (size_t)e * 4);
  float4 sb = *(const float4*)(sbias);
  float4 r;
  r.x = tanhf(a.x + b.x + sb.x);
  r.y = tanhf(a.y + b.y + sb.y);
  r.z = tanhf(a.z + b.z + sb.z);
  r.w = tanhf(a.w + b.w + sb.w);
  float ie = invE[e], iv = invV[v];
  int pe = atomicAdd(&curE[e], 1);
  int slotE = offE[e] + pe;
  csrEv[slotE] = v;
  float4 re = make_float4(r.x * ie, r.y * ie, r.z * ie, r.w * ie);
  *(float4*)(sE4 + (size_t)slotE * 4) = re;
  int pv = atomicAdd(&curV[v], 1);
  int slotV = offV[v] + pv;
  csrVe[slotV] = e;
  float4 rv = make_float4(r.x * iv, r.y * iv, r.z * iv, r.w * iv);
  *(float4*)(sV4 + (size_t)slotV * 4) = rv;
}

// ---------------- agg stage 1: full wave per edge, 8 incidences in flight ----------
// lane = hw*8 + L8; hw = incidence slot (0..7), L8 = channel octet (8 fp16 = uint4).
__global__ __launch_bounds__(256) void k_eagg(
    const __half* __restrict__ Hin, const int* __restrict__ csrEv,
    const float* __restrict__ sE4,
    const int* __restrict__ offE, const int* __restrict__ degE,
    __half* __restrict__ m)
{
  int wave = threadIdx.x >> 6, lane = threadIdx.x & 63;
  int e = blockIdx.x * 4 + wave;
  if (e >= E_N) return;
  int o0 = offE[e], dg = degE[e];
  int hw = lane >> 3, L8 = lane & 7;
  int d = L8 >> 1;
  float4 a0 = make_float4(0.f, 0.f, 0.f, 0.f);
  float4 a1 = make_float4(0.f, 0.f, 0.f, 0.f);
  for (int base = 0; base < dg; base += 8) {
    int vv = 0;
    if (lane < 8 && base + lane < dg) vv = csrEv[o0 + base + lane];
    float ss = 0.f;
    if (lane < 32 && base * 4 + lane < dg * 4) ss = sE4[(size_t)o0 * 4 + base * 4 + lane];
    int tloc = base + hw;
    int v = __shfl(vv, hw);
    float sv = __shfl(ss, hw * 4 + d);
    if (tloc < dg) {
      uint4 raw = *(const uint4*)(Hin + (size_t)v * 64 + L8 * 8);
      float2 f0 = __half22float2(*reinterpret_cast<__half2*>(&raw.x));
      float2 f1 = __half22float2(*reinterpret_cast<__half2*>(&raw.y));
      float2 f2 = __half22float2(*reinterpret_cast<__half2*>(&raw.z));
      float2 f3 = __half22float2(*reinterpret_cast<__half2*>(&raw.w));
      a0.x += sv * f0.x; a0.y += sv * f0.y; a0.z += sv * f1.x; a0.w += sv * f1.y;
      a1.x += sv * f2.x; a1.y += sv * f2.y; a1.z += sv * f3.x; a1.w += sv * f3.y;
    }
  }
  #pragma unroll
  for (int off = 8; off <= 32; off <<= 1) {
    a0.x += __shfl_xor(a0.x, off); a0.y += __shfl_xor(a0.y, off);
    a0.z += __shfl_xor(a0.z, off); a0.w += __shfl_xor(a0.w, off);
    a1.x += __shfl_xor(a1.x, off); a1.y += __shfl_xor(a1.y, off);
    a1.z += __shfl_xor(a1.z, off); a1.w += __shfl_xor(a1.w, off);
  }
  if (hw == 0) {
    __half2 o0h = __floats2half2_rn(a0.x, a0.y);
    __half2 o1h = __floats2half2_rn(a0.z, a0.w);
    __half2 o2h = __floats2half2_rn(a1.x, a1.y);
    __half2 o3h = __floats2half2_rn(a1.z, a1.w);
    uint4 o;
    o.x = *(unsigned int*)&o0h; o.y = *(unsigned int*)&o1h;
    o.z = *(unsigned int*)&o2h; o.w = *(unsigned int*)&o3h;
    *(uint4*)(m + (size_t)e * 64 + L8 * 8) = o;   // invE folded into sE4
  }
}

// ---------------- agg stage 2: half-wave per node (2 nodes/wave), 4 slots each ----
// ll = lane&31 = hw*8 + L8; s0 = lane&32 selects the half.
__global__ __launch_bounds__(256) void k_nagg(
    const __half* __restrict__ base_, const __half* __restrict__ m,
    const int* __restrict__ csrVe, const float* __restrict__ sV4,
    const int* __restrict__ offV, const int* __restrict__ degV,
    const float* __restrict__ bf0, int doRelu,
    __half* __restrict__ outH, float* __restrict__ outF)
{
  int half = threadIdx.x >> 5;               // 0..7 within block
  int v = blockIdx.x * 8 + half;
  if (v >= V_N) return;
  int lane = threadIdx.x & 63;
  int ll = lane & 31;
  int s0 = lane & 32;
  int o0 = offV[v], dg = degV[v];
  int hw = ll >> 3, L8 = ll & 7;
  int d = L8 >> 1;
  float4 a0 = make_float4(0.f, 0.f, 0.f, 0.f);
  float4 a1 = make_float4(0.f, 0.f, 0.f, 0.f);
  for (int base = 0; base < dg; base += 4) {
    int ee = 0;
    if (ll < 4 && base + ll < dg) ee = csrVe[o0 + base + ll];
    float ss = 0.f;
    if (ll < 16 && base * 4 + ll < dg * 4) ss = sV4[(size_t)o0 * 4 + base * 4 + ll];
    int tloc = base + hw;
    int e = __shfl(ee, s0 + hw);
    float sv = __shfl(ss, s0 + hw * 4 + d);
    if (tloc < dg) {
      uint4 raw = *(const uint4*)(m + (size_t)e * 64 + L8 * 8);
      float2 f0 = __half22float2(*reinterpret_cast<__half2*>(&raw.x));
      float2 f1 = __half22float2(*reinterpret_cast<__half2*>(&raw.y));
      float2 f2 = __half22float2(*reinterpret_cast<__half2*>(&raw.z));
      float2 f3 = __half22float2(*reinterpret_cast<__half2*>(&raw.w));
      a0.x += sv * f0.x; a0.y += sv * f0.y; a0.z += sv * f1.x; a0.w += sv * f1.y;
      a1.x += sv * f2.x; a1.y += sv * f2.y; a1.z += sv * f3.x; a1.w += sv * f3.y;
    }
  }
  #pragma unroll
  for (int off = 8; off <= 16; off <<= 1) {   // stays within the 32-lane half
    a0.x += __shfl_xor(a0.x, off); a0.y += __shfl_xor(a0.y, off);
    a0.z += __shfl_xor(a0.z, off); a0.w += __shfl_xor(a0.w, off);
    a1.x += __shfl_xor(a1.x, off); a1.y += __shfl_xor(a1.y, off);
    a1.z += __shfl_xor(a1.z, off); a1.w += __shfl_xor(a1.w, off);
  }
  if (hw == 0) {
    uint4 braw = *(const uint4*)(base_ + (size_t)v * 64 + L8 * 8);
    float2 b0f = __half22float2(*reinterpret_cast<__half2*>(&braw.x));
    float2 b1f = __half22float2(*reinterpret_cast<__half2*>(&braw.y));
    float2 b2f = __half22float2(*reinterpret_cast<__half2*>(&braw.z));
    float2 b3f = __half22float2(*reinterpret_cast<__half2*>(&braw.w));
    float r0 = b0f.x - a0.x, r1 = b0f.y - a0.y, r2 = b1f.x - a0.z, r3 = b1f.y - a0.w;
    float r4 = b2f.x - a1.x, r5 = b2f.y - a1.y, r6 = b3f.x - a1.z, r7 = b3f.y - a1.w;
    if (doRelu) {
      float4 bfa = *(const float4*)(bf0 + L8 * 8);
      float4 bfb = *(const float4*)(bf0 + L8 * 8 + 4);
      r0 = fmaxf(r0 + bfa.x, 0.f); r1 = fmaxf(r1 + bfa.y, 0.f);
      r2 = fmaxf(r2 + bfa.z, 0.f); r3 = fmaxf(r3 + bfa.w, 0.f);
      r4 = fmaxf(r4 + bfb.x, 0.f); r5 = fmaxf(r5 + bfb.y, 0.f);
      r6 = fmaxf(r6 + bfb.z, 0.f); r7 = fmaxf(r7 + bfb.w, 0.f);
      __half2 o0h = __floats2half2_rn(r0, r1);
      __half2 o1h = __floats2half2_rn(r2, r3);
      __half2 o2h = __floats2half2_rn(r4, r5);
      __half2 o3h = __floats2half2_rn(r6, r7);
      uint4 o;
      o.x = *(unsigned int*)&o0h; o.y = *(unsigned int*)&o1h;
      o.z = *(unsigned int*)&o2h; o.w = *(unsigned int*)&o3h;
      *(uint4*)(outH + (size_t)v * 64 + L8 * 8) = o;
    } else {
      *(float4*)(outF + (size_t)v * 64 + L8 * 8) = make_float4(r0, r1, r2, r3);
      *(float4*)(outF + (size_t)v * 64 + L8 * 8 + 4) = make_float4(r4, r5, r6, r7);
    }
  }
}

// ---------------- fused tail: register-tiled, 32 rows/block ----------------
__global__ __launch_bounds__(256) void k_final(
    const float* __restrict__ A, const float* __restrict__ W1, const float* __restrict__ b1,
    const float* __restrict__ W2, float* __restrict__ out)
{
  __shared__ float W2s[160 * 40];
  __shared__ float t[32 * 164];
  __shared__ float W1s[640];
  __shared__ float b1s[40];
  int tid = threadIdx.x;
  int v0 = blockIdx.x * 32;

  for (int k = tid; k < 1600; k += 256) ((float4*)W2s)[k] = ((const float4*)W2)[k];
  for (int k = tid; k < 640; k += 256) W1s[k] = W1[k];
  if (tid < 40) b1s[tid] = b1[tid];
  __syncthreads();

  if (tid < 160) {
    int rg = tid / 20, cg = tid % 20;
    int r0 = rg * 4;
    int j0 = cg * 8;
    int d = cg / 5;
    int jloc = j0 - d * 40;
    float a[4][16];
    #pragma unroll
    for (int i = 0; i < 4; ++i) {
      int gr = v0 + r0 + i;
      #pragma unroll
      for (int c4 = 0; c4 < 4; ++c4) {
        float4 val = make_float4(0.f, 0.f, 0.f, 0.f);
        if (gr < V_N) val = *(const float4*)(A + (size_t)gr * 64 + d * 16 + c4 * 4);
        *(float4*)&a[i][c4 * 4] = val;
      }
    }
    float acc1[4][8];
    #pragma unroll
    for (int i = 0; i < 4; ++i)
      #pragma unroll
      for (int jj = 0; jj < 8; ++jj) acc1[i][jj] = b1s[jloc + jj];
    #pragma unroll
    for (int c = 0; c < 16; ++c) {
      float w[8];
      *(float4*)&w[0] = *(const float4*)&W1s[c * 40 + jloc];
      *(float4*)&w[4] = *(const float4*)&W1s[c * 40 + jloc + 4];
      #pragma unroll
      for (int i = 0; i < 4; ++i)
        #pragma unroll
        for (int jj = 0; jj < 8; ++jj)
          acc1[i][jj] += a[i][c] * w[jj];
    }
    #pragma unroll
    for (int i = 0; i < 4; ++i) {
      float4 lo = make_float4(fmaxf(acc1[i][0], 0.f), fmaxf(acc1[i][1], 0.f),
                              fmaxf(acc1[i][2], 0.f), fmaxf(acc1[i][3], 0.f));
      float4 hi = make_float4(fmaxf(acc1[i][4], 0.f), fmaxf(acc1[i][5], 0.f),
                              fmaxf(acc1[i][6], 0.f), fmaxf(acc1[i][7], 0.f));
      *(float4*)&t[(r0 + i) * 164 + j0] = lo;
      *(float4*)&t[(r0 + i) * 164 + j0 + 4] = hi;
    }
  }
  __syncthreads();

  if (tid < 160) {
    int rg2 = tid / 10, cg2 = tid % 10;
    float acc2[2][4] = {{0.f, 0.f, 0.f, 0.f}, {0.f, 0.f, 0.f, 0.f}};
    for (int k0 = 0; k0 < 160; k0 += 4) {
      float a0[4], a1[4], w[4][4];
      *(float4*)a0 = *(const float4*)&t[(rg2 * 2 + 0) * 164 + k0];
      *(float4*)a1 = *(const float4*)&t[(rg2 * 2 + 1) * 164 + k0];
      #pragma unroll
      for (int kk = 0; kk < 4; ++kk)
        *(float4*)&w[kk][0] = *(const float4*)&W2s[(k0 + kk) * 40 + cg2 * 4];
      #pragma unroll
      for (int kk = 0; kk < 4; ++kk)
        #pragma unroll
        for (int j = 0; j < 4; ++j) {
          acc2[0][j] += a0[kk] * w[kk][j];
          acc2[1][j] += a1[kk] * w[kk][j];
        }
    }
    #pragma unroll
    for (int i = 0; i < 2; ++i) {
      int gr = v0 + rg2 * 2 + i;
      if (gr < V_N)
        *(float4*)(out + (size_t)gr * 40 + cg2 * 4) =
            make_float4(acc2[i][0], acc2[i][1], acc2[i][2], acc2[i][3]);
    }
  }
}

extern "C" void kernel_launch(void* const* d_in, const int* in_sizes, int n_in,
                              void* d_out, int out_size, void* d_ws, size_t ws_size,
                              hipStream_t stream) {
  (void)in_sizes; (void)n_in; (void)out_size; (void)ws_size;
  const float* x = (const float*)d_in[0];
  const float* eattr = (const float*)d_in[1];
  const int* node_idx = (const int*)d_in[2];
  const int* edge_idx = (const int*)d_in[3];
  const float* Wlin = (const float*)d_in[4];
  const float* blin = (const float*)d_in[5];
  const float* w1 = (const float*)d_in[6];
  const float* w2 = (const float*)d_in[7];
  const float* bs = (const float*)d_in[8];
  const float* W0 = (const float*)d_in[9];
  const float* b0 = (const float*)d_in[10];
  const float* W1 = (const float*)d_in[11];
  const float* b1 = (const float*)d_in[12];
  const float* W2 = (const float*)d_in[13];
  float* out = (float*)d_out;

  char* p = (char*)d_ws;
  auto alloc = [&](size_t bytes) { char* q = p; p += (bytes + 255) & ~(size_t)255; return q; };
  float*  Wf0   = (float*)alloc(8192 * 4);
  float*  u1    = (float*)alloc(512 * 4);
  float*  u2    = (float*)alloc(512 * 4);
  float*  cbv   = (float*)alloc(64 * 4);
  float*  bf0   = (float*)alloc(64 * 4);
  float*  sbias = (float*)alloc(4 * 4);
  __half* G0h   = (__half*)alloc((size_t)V_N * 64 * 2);
  __half* Hbh   = (__half*)alloc((size_t)V_N * 64 * 2);
  __half* mbh   = (__half*)alloc((size_t)E_N * 64 * 2);
  float*  Af    = (float*)alloc((size_t)V_N * 64 * 4);
  float*  svx   = (float*)alloc((size_t)V_N * 4 * 4);
  float*  sex   = (float*)alloc((size_t)E_N * 4 * 4);
  float*  sE4   = (float*)alloc((size_t)NNZ_N * 4 * 4);
  float*  sV4   = (float*)alloc((size_t)NNZ_N * 4 * 4);
  float*  invE  = (float*)alloc(E_N * 4);
  float*  invV  = (float*)alloc(V_N * 4);
  int* zeroRegion = (int*)alloc((size_t)(2 * E_N + 2 * V_N) * 4);
  int* degE = zeroRegion;
  int* degV = degE + E_N;
  int* curE = degV + V_N;
  int* curV = curE + E_N;
  int* offE  = (int*)alloc(E_N * 4);
  int* offV  = (int*)alloc(V_N * 4);
  int* csrEv = (int*)alloc((size_t)NNZ_N * 4);
  int* csrVe = (int*)alloc((size_t)NNZ_N * 4);
  int* bsumE = (int*)alloc(64 * 4);
  int* bsumV = (int*)alloc(64 * 4);

  int nZero = 2 * E_N + 2 * V_N;
  int nchunkE = (E_N + CHUNK - 1) / CHUNK;   // 13
  int nchunkV = (V_N + CHUNK - 1) / CHUNK;   // 25
  int nbNode = (V_N + 63) / 64;              // 782
  int nbEdge = (E_N + 63) / 64;              // 391

  hipLaunchKernelGGL(k_zero, dim3((nZero + 255) / 256), dim3(256), 0, stream, zeroRegion, nZero);
  hipLaunchKernelGGL(k_fuse, dim3(128), dim3(64), 0, stream,
                     Wlin, blin, w1, w2, bs, W0, b0, Wf0, u1, u2, cbv, bf0, sbias);
  hipLaunchKernelGGL(k_degrees, dim3((NNZ_N + 255) / 256), dim3(256), 0, stream,
                     node_idx, edge_idx, degE, degV);
  hipLaunchKernelGGL(k_scanA, dim3(nchunkE + nchunkV), dim3(256), 0, stream,
                     degE, degV, offE, offV, bsumE, bsumV, nchunkE);
  hipLaunchKernelGGL(k_scanB, dim3(2), dim3(64), 0, stream, bsumE, bsumV, nchunkE, nchunkV);
  hipLaunchKernelGGL(k_scanC_inv, dim3(nchunkE + nchunkV), dim3(256), 0, stream,
                     offE, offV, bsumE, bsumV, degE, degV, invE, invV, nchunkE);
  hipLaunchKernelGGL(k_gemm_node, dim3(nbNode), dim3(256), 0, stream,
                     x, Wf0, u1, cbv, G0h, svx);
  hipLaunchKernelGGL(k_gemm_edge, dim3(nbEdge), dim3(256), 0, stream,
                     eattr, u2, sex);
  hipLaunchKernelGGL(k_fill_s, dim3((NNZ_N + 255) / 256), dim3(256), 0, stream,
                     node_idx, edge_idx, offE, offV, curE, curV, csrEv, csrVe,
                     sE4, sV4, svx, sex, sbias, invE, invV);
  hipLaunchKernelGGL(k_eagg, dim3((E_N + 3) / 4), dim3(256), 0, stream,
                     G0h, csrEv, sE4, offE, degE, mbh);
  hipLaunchKernelGGL(k_nagg, dim3((V_N + 7) / 8), dim3(256), 0, stream,
                     G0h, mbh, csrVe, sV4, offV, degV, bf0, 1, Hbh, (float*)nullptr);
  hipLaunchKernelGGL(k_eagg, dim3((E_N + 3) / 4), dim3(256), 0, stream,
                     Hbh, csrEv, sE4, offE, degE, mbh);
  hipLaunchKernelGGL(k_nagg, dim3((V_N + 7) / 8), dim3(256), 0, stream,
                     Hbh, mbh, csrVe, sV4, offV, degV, bf0, 0, (__half*)nullptr, Af);
  hipLaunchKernelGGL(k_final, dim3((V_N + 31) / 32), dim3(256), 0, stream, Af, W1, b1, W2, out);
}